// Round 10
// baseline (232.478 us; speedup 1.0000x reference)
//
#include <hip/hip_runtime.h>
#include <cmath>

#define BB 8
#define HH 512
#define WW 512
#define HW (HH*WW)
#define RAD 15
#define SEG 32
#define EPS 0.001f
#define INV_K (1.0f/31.0f)
#define TROWS 16
#define NPX 272            // computed px per block: 256 out + 16 halo
#define XOFF (-8)

typedef _Float16 h16x8 __attribute__((ext_vector_type(8)));
typedef _Float16 h16x4 __attribute__((ext_vector_type(4)));
typedef _Float16 h16x2 __attribute__((ext_vector_type(2)));
typedef float f32x4 __attribute__((ext_vector_type(4)));
typedef float f32x2 __attribute__((ext_vector_type(2)));
typedef int   i32x4 __attribute__((ext_vector_type(4)));

static __device__ inline int s3(int r) { return (r + 6) % 3; }   // r >= -6

// ---------------- weight fragment prepack (1 wave) ----------------
__global__ __launch_bounds__(64) void k_wprep(const float* __restrict__ W1,
                                              const float* __restrict__ W2,
                                              _Float16* __restrict__ wf1,
                                              _Float16* __restrict__ wf2) {
    int lane = threadIdx.x;
    int j = lane & 15, g = lane >> 4;
#pragma unroll
    for (int cg = 0; cg < 2; ++cg)
#pragma unroll
        for (int t = 0; t < 3; ++t) {
            int s = t * 4 + g;
            h16x8 w;
#pragma unroll
            for (int i = 0; i < 8; ++i)
                w[i] = (s < 9) ? (_Float16)W1[(cg * 16 + j) * 72 + i * 9 + s] : (_Float16)0.f;
            *(h16x8*)(wf1 + ((cg * 3 + t) * 64 + lane) * 8) = w;
        }
    int ci0 = g * 8;
#pragma unroll
    for (int s = 0; s < 9; ++s) {
        h16x8 w;
#pragma unroll
        for (int i = 0; i < 8; ++i)
            w[i] = (_Float16)W2[j * 288 + (ci0 + i) * 9 + s];
        *(h16x8*)(wf2 + (s * 64 + lane) * 8) = w;
    }
}

// ------- gray + horizontal box + feats(ch0-2,4-7) fp16 -------
__global__ __launch_bounds__(256) void k_gray_hbox4(const float* __restrict__ I,
                                                    const float* __restrict__ p,
                                                    const float* __restrict__ dark,
                                                    const float* __restrict__ A,
                                                    float* __restrict__ g,
                                                    f32x4* __restrict__ hq,
                                                    _Float16* __restrict__ feats) {
    __shared__ float sg[WW], sp[WW];
    int row = blockIdx.x;            // b*HH + y
    int b = row >> 9;
    int base = row * WW;
    const float* Ib = I + (size_t)b * 3 * HW + (size_t)(row & 511) * WW;
    const float* db = dark + (size_t)base;
    _Float16 A0 = (_Float16)A[b * 3 + 0], A1 = (_Float16)A[b * 3 + 1], A2 = (_Float16)A[b * 3 + 2];
    int tid = threadIdx.x;
    for (int x = tid; x < WW; x += 256) {
        float i0 = Ib[x], i1 = Ib[HW + x], i2 = Ib[2 * HW + x];
        float gv = 0.299f * i0 + 0.587f * i1 + 0.114f * i2;
        sg[x] = gv; sp[x] = p[base + x];
        g[base + x] = gv;
        h16x8 v;
        v[0] = (_Float16)i0; v[1] = (_Float16)i1; v[2] = (_Float16)i2;
        v[3] = (_Float16)0.f;           // tg written later by k_vbox2_tg
        v[4] = (_Float16)db[x];
        v[5] = A0; v[6] = A1; v[7] = A2;
        *(h16x8*)(feats + ((size_t)base + x) * 8) = v;
    }
    __syncthreads();
    for (int x = tid; x < WW; x += 256) {
        float s0 = 0.f, s1 = 0.f, s2 = 0.f, s3v = 0.f;
        int lo = x - RAD < 0 ? 0 : x - RAD;
        int hi = x + RAD >= WW ? WW - 1 : x + RAD;
        for (int i = lo; i <= hi; ++i) {
            float gv = sg[i], pv = sp[i];
            s0 += gv; s1 += pv; s2 += gv * pv; s3v += gv * gv;
        }
        f32x4 o = { s0 * INV_K, s1 * INV_K, s2 * INV_K, s3v * INV_K };
        hq[base + x] = o;
    }
}

// ---------------- vertical box of hq, fused a/b ----------------
__global__ __launch_bounds__(256) void k_vbox4_ab(const f32x4* __restrict__ hq,
                                                  f32x2* __restrict__ ab) {
    int x = blockIdx.x * 256 + threadIdx.x;
    int b = blockIdx.y;
    int y0 = blockIdx.z * SEG;
    int pbase = b * HW + x;
    f32x4 s = { 0.f, 0.f, 0.f, 0.f };
    int r0 = y0 - RAD < 0 ? 0 : y0 - RAD;
    for (int r = r0; r < y0 + RAD; ++r) s += hq[pbase + r * WW];
    for (int y = y0; y < y0 + SEG; ++y) {
        if (y + RAD < HH) s += hq[pbase + (y + RAD) * WW];
        float mI = s[0] * INV_K, mP = s[1] * INV_K, mIp = s[2] * INV_K, mII = s[3] * INV_K;
        float cov = mIp - mI * mP;
        float var = mII - mI * mI;
        float av = cov / (var + EPS);
        float bv = mP - av * mI;
        f32x2 o = { av, bv };
        ab[pbase + y * WW] = o;
        if (y - RAD >= 0) s -= hq[pbase + (y - RAD) * WW];
    }
}

// ---------------- horizontal box of ab ----------------
__global__ __launch_bounds__(256) void k_hbox2(const f32x2* __restrict__ ab,
                                               f32x2* __restrict__ hab) {
    __shared__ float sa[WW], sb[WW];
    int base = blockIdx.x * WW;
    int tid = threadIdx.x;
    for (int x = tid; x < WW; x += 256) {
        f32x2 v = ab[base + x];
        sa[x] = v[0]; sb[x] = v[1];
    }
    __syncthreads();
    for (int x = tid; x < WW; x += 256) {
        float s0 = 0.f, s1 = 0.f;
        int lo = x - RAD < 0 ? 0 : x - RAD;
        int hi = x + RAD >= WW ? WW - 1 : x + RAD;
        for (int i = lo; i <= hi; ++i) { s0 += sa[i]; s1 += sb[i]; }
        f32x2 o = { s0 * INV_K, s1 * INV_K };
        hab[base + x] = o;
    }
}

// ------- vertical box of hab + t_guided -> tg fp32 + feats ch3 fp16 -------
__global__ __launch_bounds__(256) void k_vbox2_tg(const f32x2* __restrict__ hab,
                                                  const float* __restrict__ g,
                                                  float* __restrict__ tg,
                                                  _Float16* __restrict__ feats) {
    int x = blockIdx.x * 256 + threadIdx.x;
    int b = blockIdx.y;
    int y0 = blockIdx.z * SEG;
    int pbase = b * HW + x;
    f32x2 s = { 0.f, 0.f };
    int r0 = y0 - RAD < 0 ? 0 : y0 - RAD;
    for (int r = r0; r < y0 + RAD; ++r) s += hab[pbase + r * WW];
    for (int y = y0; y < y0 + SEG; ++y) {
        if (y + RAD < HH) s += hab[pbase + (y + RAD) * WW];
        int o = pbase + y * WW;
        float val = (s[0] * INV_K) * g[o] + (s[1] * INV_K);
        tg[o] = val;
        feats[(size_t)o * 8 + 3] = (_Float16)val;
        if (y - RAD >= 0) s -= hab[pbase + (y - RAD) * WW];
    }
}

// ---------------- fused conv1+conv2+conv3 ----------------
// h1 LDS row: [NPX px][32 ch] fp16; 16B granule c (=ch/8) at sp = c ^ ((lp>>1)&3)
static __device__ inline h16x8 ld_h1(const _Float16* hrow, int lp, int c) {
    int sp = c ^ ((lp >> 1) & 3);
    return *(const h16x8*)(hrow + lp * 32 + sp * 8);
}
static __device__ inline void st_h1(_Float16* hrow, int lp, int u, h16x4 o) {   // u = ch/4
    int sp = (u >> 1) ^ ((lp >> 1) & 3);
    *(h16x4*)(hrow + lp * 32 + sp * 8 + (u & 1) * 4) = o;
}
// h2 LDS row (1-deep): [NPX px][16 ch] fp16; granule c at sp = c ^ ((lp>>2)&1)
static __device__ inline void st_h2(_Float16* hrow, int lp, int u, h16x4 o) {   // u = ch/4
    int sp = (u >> 1) ^ ((lp >> 2) & 1);
    *(h16x4*)(hrow + lp * 16 + sp * 8 + (u & 1) * 4) = o;
}

static __device__ inline void load_b1(const _Float16* fb, int r1, int X0, int g,
                                      int j, int gq, h16x8 Bg[3]) {
    const h16x8 z = {0,0,0,0,0,0,0,0};
    bool xedgeG = (X0 == 0 && g == 0) || (X0 == 256 && g == 16);
    int gxb = X0 + XOFF + g * 16 + j;
    if (!xedgeG && r1 >= 1 && r1 <= 509) {
#pragma unroll
        for (int t = 0; t < 3; ++t) {
            int s = t * 4 + gq;
            int dy = s / 3 - 1, dx = s - (s / 3) * 3 - 1;
            Bg[t] = *(const h16x8*)(fb + ((size_t)(r1 + dy) * WW + (gxb + dx)) * 8);
        }
    } else {
#pragma unroll
        for (int t = 0; t < 3; ++t) {
            int s = t * 4 + gq;
            int dy = s / 3 - 1, dx = s - (s / 3) * 3 - 1;
            int yy = r1 + dy, xx = gxb + dx;
            bool ok = (s < 9) && yy >= 0 && yy < HH && xx >= 0 && xx < WW;
            int yc = yy < 0 ? 0 : (yy > HH - 1 ? HH - 1 : yy);
            int xc = xx < 0 ? 0 : (xx > WW - 1 ? WW - 1 : xx);
            h16x8 v = *(const h16x8*)(fb + ((size_t)yc * WW + xc) * 8);
            Bg[t] = ok ? v : z;
        }
    }
}

// gather conv2 for group 16 only (wave 4): full 3x3 window from 3-deep h1
static __device__ inline f32x4 conv2_g16(const _Float16* hr0, const _Float16* hr1,
                                         const _Float16* hr2, bool v0y, bool v2y,
                                         const h16x8* wA2, f32x4 acc,
                                         int j, int gq, int X0) {
    const h16x8 z = {0,0,0,0,0,0,0,0};
    int lpb = 16 * 16 + j;
    const _Float16* rows[3] = {hr0, hr1, hr2};
    bool vy[3] = {v0y, true, v2y};
#pragma unroll
    for (int dy = 0; dy < 3; ++dy) {
        if (vy[dy]) {
            const _Float16* hrow = rows[dy];
#pragma unroll
            for (int dx = 0; dx < 3; ++dx) {
                int lpx = lpb + dx - 1;
                int gx = X0 + XOFF + lpx;
                bool ok = (gx >= 0) && (gx < WW);
                int lpc = lpx > NPX - 1 ? NPX - 1 : lpx;
                h16x8 v = ok ? ld_h1(hrow, lpc, gq) : z;
                acc = __builtin_amdgcn_mfma_f32_16x16x32_f16(wA2[dy * 3 + dx], v, acc, 0, 0, 0);
            }
        }
    }
    return acc;
}

__global__ __launch_bounds__(512, 2) void k_cnn_fused(const _Float16* __restrict__ feats,
                                                      const _Float16* __restrict__ wf1,
                                                      const _Float16* __restrict__ wf2,
                                                      const float* __restrict__ b1,
                                                      const float* __restrict__ b2,
                                                      const float* __restrict__ W3,
                                                      const float* __restrict__ b3,
                                                      const float* __restrict__ tg,
                                                      float* __restrict__ out) {
    __shared__ _Float16 h1s[3][NPX * 32];    // 52,224 B
    __shared__ _Float16 h2s[NPX * 16];       //  8,704 B (1-deep)
    __shared__ h16x2 w3s[72];
    __shared__ float sB[48];                 // b1[32], b2[16]
    __shared__ float w3bias;

    int tid = threadIdx.x;
    int lane = tid & 63, wave = tid >> 6;
    int j = lane & 15, gq = lane >> 4;
    int b = blockIdx.y;
    int X0 = (blockIdx.x & 1) * 256;
    int y0 = (blockIdx.x >> 1) * TROWS;
    const _Float16* fb = feats + (size_t)b * HW * 8;
    const float* tgb = tg + (size_t)b * HW;
    float* outb = out + (size_t)b * HW;

    const h16x8* wf1v = (const h16x8*)wf1;
    const h16x8* wf2v = (const h16x8*)wf2;
    h16x8 wA1[2][3], wA2[9];
#pragma unroll
    for (int cg = 0; cg < 2; ++cg)
#pragma unroll
        for (int t = 0; t < 3; ++t) wA1[cg][t] = wf1v[(cg * 3 + t) * 64 + lane];
#pragma unroll
    for (int s = 0; s < 9; ++s) wA2[s] = wf2v[s * 64 + lane];
    if (tid < 72) {
        int s = tid >> 3, u = tid & 7;
        h16x2 w;
        w[0] = (_Float16)W3[(2 * u) * 9 + s];
        w[1] = (_Float16)W3[(2 * u + 1) * 9 + s];
        w3s[tid] = w;
    } else if (tid < 104) {
        sB[tid - 72] = b1[tid - 72];
    } else if (tid < 120) {
        sB[32 + tid - 104] = b2[tid - 104];
    } else if (tid == 120) w3bias = b3[0];
    __syncthreads();

    int g0 = wave * 2;
    const h16x8 z16 = {0,0,0,0,0,0,0,0};
    h16x8 Bv[2][3];                 // conv1 B prefetch, groups {g0, g0+1}
    // conv2 scatter accumulators: cA oldest (completes), cC newest
    f32x4 cA[2] = {}, cB[2] = {}, cC[2] = {};
    f32x4 cg16 = {};                // gather accumulator (wave 4)
    int c3px = tid >> 1, c3h = tid & 1;
    float accN = 0.f, accC = 0.f;

    for (int i = 0; i < TROWS + 5; ++i) {
        int r1 = y0 + i - 2;          // h1 row conv1 produces this iter
        int rp = y0 + i - 3;          // h1 row scatter-consumed this iter
        int r2 = y0 + i - 4;          // h2 row completed this iter
        bool do_h1 = (i <= TROWS + 3) && (r1 >= 0) && (r1 <= 511);
        bool do_rp = (i >= 1) && (rp >= 0) && (rp <= 511);
        bool st_r2 = (r2 >= 0) && (r2 <= 511);

        // ---- P1a: issue feats global loads for h1 row r1 (prefetch) ----
        if (do_h1) {
#pragma unroll
            for (int k = 0; k < 2; ++k)
                load_b1(fb, r1, X0, g0 + k, j, gq, Bv[k]);
        }

        // ---- P1b: conv2 scatter — read h1[rp] once, update 3 row-accs ----
        // rotate: cA (row rp-1, completes) <- cB <- cC <- bias2
        f32x4 bias2v = *(const f32x4*)(sB + 32 + gq * 4);
#pragma unroll
        for (int k = 0; k < 2; ++k) {
            cA[k] = cB[k]; cB[k] = cC[k]; cC[k] = bias2v;
        }
        if (do_rp) {
            const _Float16* hrow = h1s[s3(rp)];
#pragma unroll
            for (int k = 0; k < 2; ++k) {
                int g = g0 + k;
                int lpb = g * 16 + j;
#pragma unroll
                for (int dx = 0; dx < 3; ++dx) {
                    int lpx = lpb + dx - 1;
                    h16x8 v;
                    if (wave == 0 && k == 0) {
                        int lpc = lpx < 0 ? 0 : lpx;
                        v = ld_h1(hrow, lpc, gq);
                        if (X0 == 0) v = (lpx >= 8) ? v : z16;   // src x >= 0
                    } else {
                        v = ld_h1(hrow, lpx, gq);
                    }
                    cC[k] = __builtin_amdgcn_mfma_f32_16x16x32_f16(wA2[0 + dx], v, cC[k], 0, 0, 0);
                    cB[k] = __builtin_amdgcn_mfma_f32_16x16x32_f16(wA2[3 + dx], v, cB[k], 0, 0, 0);
                    cA[k] = __builtin_amdgcn_mfma_f32_16x16x32_f16(wA2[6 + dx], v, cA[k], 0, 0, 0);
                }
            }
        }
        if (st_r2) {
#pragma unroll
            for (int k = 0; k < 2; ++k) {
                h16x4 o;
#pragma unroll
                for (int r = 0; r < 4; ++r) o[r] = (_Float16)fmaxf(cA[k][r], 0.f);
                st_h2(h2s, (g0 + k) * 16 + j, gq, o);
            }
            if (wave == 4) {      // group 16: gather from 3-deep h1
                f32x4 a2 = bias2v;
                a2 = conv2_g16(h1s[s3(r2 - 1)], h1s[s3(r2)], h1s[s3(r2 + 1)],
                               r2 - 1 >= 0, r2 + 1 <= 511, wA2, a2, j, gq, X0);
                h16x4 o;
#pragma unroll
                for (int r = 0; r < 4; ++r) o[r] = (_Float16)fmaxf(a2[r], 0.f);
                st_h2(h2s, 16 * 16 + j, gq, o);
            }
        }
        __syncthreads();

        // ---- P2a: conv1 MFMA + store h1 row r1 ----
        if (do_h1) {
            _Float16* h1row = h1s[s3(r1)];
#pragma unroll
            for (int k = 0; k < 2; ++k) {
                f32x4 a1[2];
                a1[0] = *(const f32x4*)(sB + gq * 4);
                a1[1] = *(const f32x4*)(sB + 16 + gq * 4);
#pragma unroll
                for (int t = 0; t < 3; ++t)
#pragma unroll
                    for (int cg = 0; cg < 2; ++cg)
                        a1[cg] = __builtin_amdgcn_mfma_f32_16x16x32_f16(wA1[cg][t], Bv[k][t], a1[cg], 0, 0, 0);
                int lp = (g0 + k) * 16 + j;
#pragma unroll
                for (int cg = 0; cg < 2; ++cg) {
                    h16x4 o;
#pragma unroll
                    for (int r = 0; r < 4; ++r) o[r] = (_Float16)fmaxf(a1[cg][r], 0.f);
                    st_h1(h1row, lp, cg * 4 + gq, o);
                }
            }
            if (wave == 4) {      // group 16 conv1: load at-use (short-lived regs)
                h16x8 Bg[3];
                load_b1(fb, r1, X0, 16, j, gq, Bg);
                f32x4 a1[2];
                a1[0] = *(const f32x4*)(sB + gq * 4);
                a1[1] = *(const f32x4*)(sB + 16 + gq * 4);
#pragma unroll
                for (int t = 0; t < 3; ++t)
#pragma unroll
                    for (int cg = 0; cg < 2; ++cg)
                        a1[cg] = __builtin_amdgcn_mfma_f32_16x16x32_f16(wA1[cg][t], Bg[t], a1[cg], 0, 0, 0);
                int lp = 16 * 16 + j;
#pragma unroll
                for (int cg = 0; cg < 2; ++cg) {
                    h16x4 o;
#pragma unroll
                    for (int r = 0; r < 4; ++r) o[r] = (_Float16)fmaxf(a1[cg][r], 0.f);
                    st_h1(h1row, lp, cg * 4 + gq, o);
                }
            }
        }

        // ---- P2b: conv3 (512 threads, 8 ch each) + blend + store out ----
        {
            float d0 = 0.f, d1 = 0.f, d2 = 0.f;
            if (st_r2) {
#pragma unroll
                for (int dx = 0; dx < 3; ++dx) {
                    int xim = X0 + c3px + dx - 1;
                    if (xim >= 0 && xim < WW) {
                        int lpx = c3px + 8 + dx - 1;
                        int sp = c3h ^ ((lpx >> 2) & 1);
                        h16x8 v = *(const h16x8*)(h2s + lpx * 16 + sp * 8);
#pragma unroll
                        for (int q = 0; q < 4; ++q) {
                            h16x2 pv = { v[2 * q], v[2 * q + 1] };
                            d0 = __builtin_amdgcn_fdot2(pv, w3s[(0 + dx) * 8 + 4 * c3h + q], d0, false);
                            d1 = __builtin_amdgcn_fdot2(pv, w3s[(3 + dx) * 8 + 4 * c3h + q], d1, false);
                            d2 = __builtin_amdgcn_fdot2(pv, w3s[(6 + dx) * 8 + 4 * c3h + q], d2, false);
                        }
                    }
                }
            }
            if (i >= 5) {
                float accv = accC + d2;
                float full = accv + __shfl_xor(accv, 1) + w3bias;
                if (c3h == 0) {
                    float sg = 1.f / (1.f + expf(-full));
                    int o = (r2 - 1) * WW + X0 + c3px;
                    float tf = 0.7f * tgb[o] + 0.3f * sg;
                    outb[o] = fminf(fmaxf(tf, 0.f), 1.f);
                }
            }
            accC = accN + d1;
            accN = d0;
        }
        __syncthreads();
    }
}

extern "C" void kernel_launch(void* const* d_in, const int* in_sizes, int n_in,
                              void* d_out, int out_size, void* d_ws, size_t ws_size,
                              hipStream_t stream) {
    const float* I    = (const float*)d_in[0];
    const float* t0   = (const float*)d_in[1];
    const float* dark = (const float*)d_in[2];
    const float* A    = (const float*)d_in[3];
    const float* W1   = (const float*)d_in[4];
    const float* b1   = (const float*)d_in[5];
    const float* W2   = (const float*)d_in[6];
    const float* b2   = (const float*)d_in[7];
    const float* W3   = (const float*)d_in[8];
    const float* b3   = (const float*)d_in[9];
    float* out = (float*)d_out;
    float* ws  = (float*)d_ws;

    const size_t P = (size_t)BB * HW;       // 2M floats = 8 MB
    float* tg       = ws;                    // [0,P)   fp32
    _Float16* feats = (_Float16*)(ws + P);   // [P,5P)  fp16 [B][HW][8]
    float* g        = ws + 5 * P;            // [5P,6P)
    f32x4* hq       = (f32x4*)(ws + 6 * P);  // [6P,10P)
    f32x2* ab       = (f32x2*)(ws + 10 * P); // [10P,12P)
    f32x2* hab      = (f32x2*)(ws + 12 * P); // [12P,14P)
    _Float16* wf1   = (_Float16*)(ws + 14 * P);  // 3072 halves
    _Float16* wf2   = wf1 + 6 * 64 * 8;          // 4608 halves

    k_wprep<<<1, 64, 0, stream>>>(W1, W2, wf1, wf2);
    k_gray_hbox4<<<BB * HH, 256, 0, stream>>>(I, t0, dark, A, g, hq, feats);
    dim3 gv(WW / 256, BB, HH / SEG);
    k_vbox4_ab<<<gv, 256, 0, stream>>>(hq, ab);
    k_hbox2<<<BB * HH, 256, 0, stream>>>(ab, hab);
    k_vbox2_tg<<<gv, 256, 0, stream>>>(hab, g, tg, feats);

    dim3 gf(64, BB);                        // 32 y-tiles x 2 x-halves x 8 batches
    k_cnn_fused<<<gf, 512, 0, stream>>>(feats, wf1, wf2, b1, b2, W3, b3, tg, out);
}

// Round 11
// 215.053 us; speedup vs baseline: 1.0810x; 1.0810x over previous
//
#include <hip/hip_runtime.h>
#include <cmath>

#define BB 8
#define HH 512
#define WW 512
#define HW (HH*WW)
#define RAD 15
#define SEG 32
#define EPS 0.001f
#define INV_K (1.0f/31.0f)
#define TROWS 16
#define NPX 272            // computed px per block: 256 out + 16 halo
#define XOFF (-8)

typedef _Float16 h16x8 __attribute__((ext_vector_type(8)));
typedef _Float16 h16x4 __attribute__((ext_vector_type(4)));
typedef _Float16 h16x2 __attribute__((ext_vector_type(2)));
typedef float f32x4 __attribute__((ext_vector_type(4)));
typedef float f32x2 __attribute__((ext_vector_type(2)));
typedef int   i32x4 __attribute__((ext_vector_type(4)));

static __device__ inline int s3(int r) { return (r + 6) % 3; }   // r >= -6

// ---------------- weight fragment prepack (1 wave) ----------------
__global__ __launch_bounds__(64) void k_wprep(const float* __restrict__ W1,
                                              const float* __restrict__ W2,
                                              _Float16* __restrict__ wf1,
                                              _Float16* __restrict__ wf2) {
    int lane = threadIdx.x;
    int j = lane & 15, g = lane >> 4;
#pragma unroll
    for (int cg = 0; cg < 2; ++cg)
#pragma unroll
        for (int t = 0; t < 3; ++t) {
            int s = t * 4 + g;
            h16x8 w;
#pragma unroll
            for (int i = 0; i < 8; ++i)
                w[i] = (s < 9) ? (_Float16)W1[(cg * 16 + j) * 72 + i * 9 + s] : (_Float16)0.f;
            *(h16x8*)(wf1 + ((cg * 3 + t) * 64 + lane) * 8) = w;
        }
    int ci0 = g * 8;
#pragma unroll
    for (int s = 0; s < 9; ++s) {
        h16x8 w;
#pragma unroll
        for (int i = 0; i < 8; ++i)
            w[i] = (_Float16)W2[j * 288 + (ci0 + i) * 9 + s];
        *(h16x8*)(wf2 + (s * 64 + lane) * 8) = w;
    }
}

// ------- gray + horizontal box + feats(ch0-2,4-7) fp16 -------
__global__ __launch_bounds__(256) void k_gray_hbox4(const float* __restrict__ I,
                                                    const float* __restrict__ p,
                                                    const float* __restrict__ dark,
                                                    const float* __restrict__ A,
                                                    float* __restrict__ g,
                                                    f32x4* __restrict__ hq,
                                                    _Float16* __restrict__ feats) {
    __shared__ float sg[WW], sp[WW];
    int row = blockIdx.x;            // b*HH + y
    int b = row >> 9;
    int base = row * WW;
    const float* Ib = I + (size_t)b * 3 * HW + (size_t)(row & 511) * WW;
    const float* db = dark + (size_t)base;
    _Float16 A0 = (_Float16)A[b * 3 + 0], A1 = (_Float16)A[b * 3 + 1], A2 = (_Float16)A[b * 3 + 2];
    int tid = threadIdx.x;
    for (int x = tid; x < WW; x += 256) {
        float i0 = Ib[x], i1 = Ib[HW + x], i2 = Ib[2 * HW + x];
        float gv = 0.299f * i0 + 0.587f * i1 + 0.114f * i2;
        sg[x] = gv; sp[x] = p[base + x];
        g[base + x] = gv;
        h16x8 v;
        v[0] = (_Float16)i0; v[1] = (_Float16)i1; v[2] = (_Float16)i2;
        v[3] = (_Float16)0.f;           // tg written later by k_vbox2_tg
        v[4] = (_Float16)db[x];
        v[5] = A0; v[6] = A1; v[7] = A2;
        *(h16x8*)(feats + ((size_t)base + x) * 8) = v;
    }
    __syncthreads();
    for (int x = tid; x < WW; x += 256) {
        float s0 = 0.f, s1 = 0.f, s2 = 0.f, s3v = 0.f;
        int lo = x - RAD < 0 ? 0 : x - RAD;
        int hi = x + RAD >= WW ? WW - 1 : x + RAD;
        for (int i = lo; i <= hi; ++i) {
            float gv = sg[i], pv = sp[i];
            s0 += gv; s1 += pv; s2 += gv * pv; s3v += gv * gv;
        }
        f32x4 o = { s0 * INV_K, s1 * INV_K, s2 * INV_K, s3v * INV_K };
        hq[base + x] = o;
    }
}

// ---------------- vertical box of hq, fused a/b ----------------
__global__ __launch_bounds__(256) void k_vbox4_ab(const f32x4* __restrict__ hq,
                                                  f32x2* __restrict__ ab) {
    int x = blockIdx.x * 256 + threadIdx.x;
    int b = blockIdx.y;
    int y0 = blockIdx.z * SEG;
    int pbase = b * HW + x;
    f32x4 s = { 0.f, 0.f, 0.f, 0.f };
    int r0 = y0 - RAD < 0 ? 0 : y0 - RAD;
    for (int r = r0; r < y0 + RAD; ++r) s += hq[pbase + r * WW];
    for (int y = y0; y < y0 + SEG; ++y) {
        if (y + RAD < HH) s += hq[pbase + (y + RAD) * WW];
        float mI = s[0] * INV_K, mP = s[1] * INV_K, mIp = s[2] * INV_K, mII = s[3] * INV_K;
        float cov = mIp - mI * mP;
        float var = mII - mI * mI;
        float av = cov / (var + EPS);
        float bv = mP - av * mI;
        f32x2 o = { av, bv };
        ab[pbase + y * WW] = o;
        if (y - RAD >= 0) s -= hq[pbase + (y - RAD) * WW];
    }
}

// ---------------- horizontal box of ab ----------------
__global__ __launch_bounds__(256) void k_hbox2(const f32x2* __restrict__ ab,
                                               f32x2* __restrict__ hab) {
    __shared__ float sa[WW], sb[WW];
    int base = blockIdx.x * WW;
    int tid = threadIdx.x;
    for (int x = tid; x < WW; x += 256) {
        f32x2 v = ab[base + x];
        sa[x] = v[0]; sb[x] = v[1];
    }
    __syncthreads();
    for (int x = tid; x < WW; x += 256) {
        float s0 = 0.f, s1 = 0.f;
        int lo = x - RAD < 0 ? 0 : x - RAD;
        int hi = x + RAD >= WW ? WW - 1 : x + RAD;
        for (int i = lo; i <= hi; ++i) { s0 += sa[i]; s1 += sb[i]; }
        f32x2 o = { s0 * INV_K, s1 * INV_K };
        hab[base + x] = o;
    }
}

// ------- vertical box of hab + t_guided -> tg fp32 + feats ch3 fp16 -------
__global__ __launch_bounds__(256) void k_vbox2_tg(const f32x2* __restrict__ hab,
                                                  const float* __restrict__ g,
                                                  float* __restrict__ tg,
                                                  _Float16* __restrict__ feats) {
    int x = blockIdx.x * 256 + threadIdx.x;
    int b = blockIdx.y;
    int y0 = blockIdx.z * SEG;
    int pbase = b * HW + x;
    f32x2 s = { 0.f, 0.f };
    int r0 = y0 - RAD < 0 ? 0 : y0 - RAD;
    for (int r = r0; r < y0 + RAD; ++r) s += hab[pbase + r * WW];
    for (int y = y0; y < y0 + SEG; ++y) {
        if (y + RAD < HH) s += hab[pbase + (y + RAD) * WW];
        int o = pbase + y * WW;
        float val = (s[0] * INV_K) * g[o] + (s[1] * INV_K);
        tg[o] = val;
        feats[(size_t)o * 8 + 3] = (_Float16)val;
        if (y - RAD >= 0) s -= hab[pbase + (y - RAD) * WW];
    }
}

// ---------------- fused conv1+conv2+conv3, single barrier per row ----------------
// h1 LDS row: [NPX px][32 ch] fp16; 16B granule c (=ch/8) at sp = c ^ ((lp>>1)&3)
static __device__ inline h16x8 ld_h1(const _Float16* hrow, int lp, int c) {
    int sp = c ^ ((lp >> 1) & 3);
    return *(const h16x8*)(hrow + lp * 32 + sp * 8);
}
static __device__ inline void st_h1(_Float16* hrow, int lp, int u, h16x4 o) {   // u = ch/4
    int sp = (u >> 1) ^ ((lp >> 1) & 3);
    *(h16x4*)(hrow + lp * 32 + sp * 8 + (u & 1) * 4) = o;
}
// h2 LDS row: [NPX px][16 ch] fp16; granule c at sp = c ^ ((lp>>2)&1)
static __device__ inline void st_h2(_Float16* hrow, int lp, int u, h16x4 o) {   // u = ch/4
    int sp = (u >> 1) ^ ((lp >> 2) & 1);
    *(h16x4*)(hrow + lp * 16 + sp * 8 + (u & 1) * 4) = o;
}

static __device__ inline void load_b1(const _Float16* fb, int r1, int X0, int g,
                                      int j, int gq, h16x8 Bg[3]) {
    const h16x8 z = {0,0,0,0,0,0,0,0};
    bool xedgeG = (X0 == 0 && g == 0) || (X0 == 256 && g == 16);
    int gxb = X0 + XOFF + g * 16 + j;
    if (!xedgeG && r1 >= 1 && r1 <= 509) {
#pragma unroll
        for (int t = 0; t < 3; ++t) {
            int s = t * 4 + gq;
            int dy = s / 3 - 1, dx = s - (s / 3) * 3 - 1;
            Bg[t] = *(const h16x8*)(fb + ((size_t)(r1 + dy) * WW + (gxb + dx)) * 8);
        }
    } else {
#pragma unroll
        for (int t = 0; t < 3; ++t) {
            int s = t * 4 + gq;
            int dy = s / 3 - 1, dx = s - (s / 3) * 3 - 1;
            int yy = r1 + dy, xx = gxb + dx;
            bool ok = (s < 9) && yy >= 0 && yy < HH && xx >= 0 && xx < WW;
            int yc = yy < 0 ? 0 : (yy > HH - 1 ? HH - 1 : yy);
            int xc = xx < 0 ? 0 : (xx > WW - 1 ? WW - 1 : xx);
            h16x8 v = *(const h16x8*)(fb + ((size_t)yc * WW + xc) * 8);
            Bg[t] = ok ? v : z;
        }
    }
}

__global__ __launch_bounds__(512, 2) void k_cnn_fused(const _Float16* __restrict__ feats,
                                                      const _Float16* __restrict__ wf1,
                                                      const _Float16* __restrict__ wf2,
                                                      const float* __restrict__ b1,
                                                      const float* __restrict__ b2,
                                                      const float* __restrict__ W3,
                                                      const float* __restrict__ b3,
                                                      const float* __restrict__ tg,
                                                      float* __restrict__ out) {
    __shared__ _Float16 h1s[3][NPX * 32];    // 52,224 B
    __shared__ _Float16 h2s2[2][NPX * 16];   // 17,408 B (slot parity = row & 1)
    __shared__ h16x8 wf1s[6 * 64];           //  6,144 B
    __shared__ h16x2 w3s[72];
    __shared__ float sB[48];                 // b1[32], b2[16]
    __shared__ float w3bias;

    int tid = threadIdx.x;
    int lane = tid & 63, wave = tid >> 6;
    int j = lane & 15, gq = lane >> 4;
    int b = blockIdx.y;
    int X0 = (blockIdx.x & 1) * 256;
    int y0 = (blockIdx.x >> 1) * TROWS;
    const _Float16* fb = feats + (size_t)b * HW * 8;
    const float* tgb = tg + (size_t)b * HW;
    float* outb = out + (size_t)b * HW;

    // stage wf1 into LDS (384 x 16B), wA2 into regs
    for (int q = tid; q < 384; q += 512)
        ((i32x4*)wf1s)[q] = ((const i32x4*)wf1)[q];
    const h16x8* wf2v = (const h16x8*)wf2;
    h16x8 wA2[9];
#pragma unroll
    for (int s = 0; s < 9; ++s) wA2[s] = wf2v[s * 64 + lane];
    if (tid < 72) {
        int s = tid >> 3, u = tid & 7;
        h16x2 w;
        w[0] = (_Float16)W3[(2 * u) * 9 + s];
        w[1] = (_Float16)W3[(2 * u + 1) * 9 + s];
        w3s[tid] = w;
    } else if (tid < 104) {
        sB[tid - 72] = b1[tid - 72];
    } else if (tid < 120) {
        sB[32 + tid - 104] = b2[tid - 104];
    } else if (tid == 120) w3bias = b3[0];
    __syncthreads();

    int g0 = wave * 2;
    const h16x8 z16 = {0,0,0,0,0,0,0,0};
    h16x8 Bv[2][3];                  // conv1 B prefetch, groups {g0, g0+1}
    h16x8 Bg[3];                     // g16 conv1 B (wave 4)
    f32x4 cA[2] = {}, cB[2] = {}, cC[2] = {};   // conv2 scatter accs
    f32x4 gA = {}, gB = {}, gC = {};            // g16 scatter accs (wave 4)
    int c3px = tid >> 1, c3h = tid & 1;
    float accN = 0.f, accC3 = 0.f;

    for (int i = 0; i < TROWS + 6; ++i) {       // 22 iterations, 1 barrier each
        int r1 = y0 + i - 2;          // conv1 produces h1[r1]
        int rp = y0 + i - 3;          // conv2-scatter consumes h1[rp]
        int r2 = y0 + i - 4;          // h2 row completed + stored
        int R  = y0 + i - 5;          // h2 row conv3 reads (written last iter)
        bool do_h1 = (i <= TROWS + 3) && (r1 >= 0) && (r1 <= 511);
        bool do_rp = (i >= 1) && (i <= TROWS + 4) && (rp >= 0) && (rp <= 511);
        bool st_r2 = (i <= TROWS + 4) && (r2 >= 0) && (r2 <= 511);
        bool rd_R  = (R >= 0) && (R <= 511);

        // ---- A: issue conv1 global loads (drain under B/C/D) ----
        if (do_h1) {
#pragma unroll
            for (int k = 0; k < 2; ++k)
                load_b1(fb, r1, X0, g0 + k, j, gq, Bv[k]);
            if (wave == 4) load_b1(fb, r1, X0, 16, j, gq, Bg);
        }

        // ---- B: conv2 scatter — read h1[rp] once, update 3 row-accs ----
        f32x4 bias2v = *(const f32x4*)(sB + 32 + gq * 4);
#pragma unroll
        for (int k = 0; k < 2; ++k) {
            cA[k] = cB[k]; cB[k] = cC[k]; cC[k] = bias2v;
        }
        if (wave == 4) { gA = gB; gB = gC; gC = bias2v; }
        if (do_rp) {
            const _Float16* hrow = h1s[s3(rp)];
#pragma unroll
            for (int k = 0; k < 2; ++k) {
                int lpb = (g0 + k) * 16 + j;
#pragma unroll
                for (int dx = 0; dx < 3; ++dx) {
                    int lpx = lpb + dx - 1;
                    h16x8 v;
                    if (wave == 0 && k == 0) {
                        int lpc = lpx < 0 ? 0 : lpx;
                        v = ld_h1(hrow, lpc, gq);
                        if (X0 == 0) v = (lpx >= 8) ? v : z16;   // src x >= 0
                    } else {
                        v = ld_h1(hrow, lpx, gq);
                    }
                    cC[k] = __builtin_amdgcn_mfma_f32_16x16x32_f16(wA2[0 + dx], v, cC[k], 0, 0, 0);
                    cB[k] = __builtin_amdgcn_mfma_f32_16x16x32_f16(wA2[3 + dx], v, cB[k], 0, 0, 0);
                    cA[k] = __builtin_amdgcn_mfma_f32_16x16x32_f16(wA2[6 + dx], v, cA[k], 0, 0, 0);
                }
            }
            if (wave == 4) {                      // group 16 scatter
                int lpb = 256 + j;
#pragma unroll
                for (int dx = 0; dx < 3; ++dx) {
                    int lpx = lpb + dx - 1;       // 255..272
                    int lpc = lpx > NPX - 1 ? NPX - 1 : lpx;
                    h16x8 v = ld_h1(hrow, lpc, gq);
                    if (X0 == 256 && lpx > 263) v = z16;   // src x < WW
                    gC = __builtin_amdgcn_mfma_f32_16x16x32_f16(wA2[0 + dx], v, gC, 0, 0, 0);
                    gB = __builtin_amdgcn_mfma_f32_16x16x32_f16(wA2[3 + dx], v, gB, 0, 0, 0);
                    gA = __builtin_amdgcn_mfma_f32_16x16x32_f16(wA2[6 + dx], v, gA, 0, 0, 0);
                }
            }
        }

        // ---- C: store completed h2 row r2 (slot r2&1; conv3 reads slot R&1) ----
        if (st_r2) {
            _Float16* h2row = h2s2[r2 & 1];
#pragma unroll
            for (int k = 0; k < 2; ++k) {
                h16x4 o;
#pragma unroll
                for (int r = 0; r < 4; ++r) o[r] = (_Float16)fmaxf(cA[k][r], 0.f);
                st_h2(h2row, (g0 + k) * 16 + j, gq, o);
            }
            if (wave == 4) {
                h16x4 o;
#pragma unroll
                for (int r = 0; r < 4; ++r) o[r] = (_Float16)fmaxf(gA[r], 0.f);
                st_h2(h2row, 256 + j, gq, o);
            }
        }

        // ---- D: conv3 running-partials on h2 row R (written last iter) ----
        {
            float d0 = 0.f, d1 = 0.f, d2 = 0.f;
            if (rd_R) {
                const _Float16* hrow = h2s2[R & 1];
#pragma unroll
                for (int dx = 0; dx < 3; ++dx) {
                    int xim = X0 + c3px + dx - 1;
                    if (xim >= 0 && xim < WW) {
                        int lpx = c3px + 8 + dx - 1;
                        int sp = c3h ^ ((lpx >> 2) & 1);
                        h16x8 v = *(const h16x8*)(hrow + lpx * 16 + sp * 8);
#pragma unroll
                        for (int q = 0; q < 4; ++q) {
                            h16x2 pv = { v[2 * q], v[2 * q + 1] };
                            d0 = __builtin_amdgcn_fdot2(pv, w3s[(0 + dx) * 8 + 4 * c3h + q], d0, false);
                            d1 = __builtin_amdgcn_fdot2(pv, w3s[(3 + dx) * 8 + 4 * c3h + q], d1, false);
                            d2 = __builtin_amdgcn_fdot2(pv, w3s[(6 + dx) * 8 + 4 * c3h + q], d2, false);
                        }
                    }
                }
            }
            if (i >= 6) {
                float accv = accC3 + d2;
                float full = accv + __shfl_xor(accv, 1) + w3bias;
                if (c3h == 0) {
                    float sg = 1.f / (1.f + expf(-full));
                    int o = (y0 + i - 6) * WW + X0 + c3px;
                    float tf = 0.7f * tgb[o] + 0.3f * sg;
                    outb[o] = fminf(fmaxf(tf, 0.f), 1.f);
                }
            }
            accC3 = accN + d1;
            accN = d0;
        }

        // ---- E: conv1 MFMA (Bv drained) + store h1 row r1 ----
        if (do_h1) {
            h16x8 w1[2][3];
#pragma unroll
            for (int cg = 0; cg < 2; ++cg)
#pragma unroll
                for (int t = 0; t < 3; ++t) w1[cg][t] = wf1s[(cg * 3 + t) * 64 + lane];
            _Float16* h1row = h1s[s3(r1)];
            f32x4 b1lo = *(const f32x4*)(sB + gq * 4);
            f32x4 b1hi = *(const f32x4*)(sB + 16 + gq * 4);
#pragma unroll
            for (int k = 0; k < 2; ++k) {
                f32x4 a1[2] = { b1lo, b1hi };
#pragma unroll
                for (int t = 0; t < 3; ++t)
#pragma unroll
                    for (int cg = 0; cg < 2; ++cg)
                        a1[cg] = __builtin_amdgcn_mfma_f32_16x16x32_f16(w1[cg][t], Bv[k][t], a1[cg], 0, 0, 0);
                int lp = (g0 + k) * 16 + j;
#pragma unroll
                for (int cg = 0; cg < 2; ++cg) {
                    h16x4 o;
#pragma unroll
                    for (int r = 0; r < 4; ++r) o[r] = (_Float16)fmaxf(a1[cg][r], 0.f);
                    st_h1(h1row, lp, cg * 4 + gq, o);
                }
            }
            if (wave == 4) {
                f32x4 a1[2] = { b1lo, b1hi };
#pragma unroll
                for (int t = 0; t < 3; ++t)
#pragma unroll
                    for (int cg = 0; cg < 2; ++cg)
                        a1[cg] = __builtin_amdgcn_mfma_f32_16x16x32_f16(w1[cg][t], Bg[t], a1[cg], 0, 0, 0);
                int lp = 256 + j;
#pragma unroll
                for (int cg = 0; cg < 2; ++cg) {
                    h16x4 o;
#pragma unroll
                    for (int r = 0; r < 4; ++r) o[r] = (_Float16)fmaxf(a1[cg][r], 0.f);
                    st_h1(h1row, lp, cg * 4 + gq, o);
                }
            }
        }
        __syncthreads();
    }
}

extern "C" void kernel_launch(void* const* d_in, const int* in_sizes, int n_in,
                              void* d_out, int out_size, void* d_ws, size_t ws_size,
                              hipStream_t stream) {
    const float* I    = (const float*)d_in[0];
    const float* t0   = (const float*)d_in[1];
    const float* dark = (const float*)d_in[2];
    const float* A    = (const float*)d_in[3];
    const float* W1   = (const float*)d_in[4];
    const float* b1   = (const float*)d_in[5];
    const float* W2   = (const float*)d_in[6];
    const float* b2   = (const float*)d_in[7];
    const float* W3   = (const float*)d_in[8];
    const float* b3   = (const float*)d_in[9];
    float* out = (float*)d_out;
    float* ws  = (float*)d_ws;

    const size_t P = (size_t)BB * HW;       // 2M floats = 8 MB
    float* tg       = ws;                    // [0,P)   fp32
    _Float16* feats = (_Float16*)(ws + P);   // [P,5P)  fp16 [B][HW][8]
    float* g        = ws + 5 * P;            // [5P,6P)
    f32x4* hq       = (f32x4*)(ws + 6 * P);  // [6P,10P)
    f32x2* ab       = (f32x2*)(ws + 10 * P); // [10P,12P)
    f32x2* hab      = (f32x2*)(ws + 12 * P); // [12P,14P)
    _Float16* wf1   = (_Float16*)(ws + 14 * P);  // 3072 halves
    _Float16* wf2   = wf1 + 6 * 64 * 8;          // 4608 halves

    k_wprep<<<1, 64, 0, stream>>>(W1, W2, wf1, wf2);
    k_gray_hbox4<<<BB * HH, 256, 0, stream>>>(I, t0, dark, A, g, hq, feats);
    dim3 gv(WW / 256, BB, HH / SEG);
    k_vbox4_ab<<<gv, 256, 0, stream>>>(hq, ab);
    k_hbox2<<<BB * HH, 256, 0, stream>>>(ab, hab);
    k_vbox2_tg<<<gv, 256, 0, stream>>>(hab, g, tg, feats);

    dim3 gf(64, BB);                        // 32 y-tiles x 2 x-halves x 8 batches
    k_cnn_fused<<<gf, 512, 0, stream>>>(feats, wf1, wf2, b1, b2, W3, b3, tg, out);
}

// Round 12
// 199.035 us; speedup vs baseline: 1.1680x; 1.0805x over previous
//
#include <hip/hip_runtime.h>
#include <cmath>

#define BB 8
#define HH 512
#define WW 512
#define HW (HH*WW)
#define RAD 15
#define SEG 16
#define EPS 0.001f
#define INV_K (1.0f/31.0f)
#define TROWS 16
#define NPX 272            // computed px per block: 256 out + 16 halo
#define XOFF (-8)

typedef _Float16 h16x8 __attribute__((ext_vector_type(8)));
typedef _Float16 h16x4 __attribute__((ext_vector_type(4)));
typedef _Float16 h16x2 __attribute__((ext_vector_type(2)));
typedef float f32x4 __attribute__((ext_vector_type(4)));
typedef float f32x2 __attribute__((ext_vector_type(2)));
typedef int   i32x4 __attribute__((ext_vector_type(4)));

static __device__ inline int s3(int r) { return (r + 6) % 3; }   // r >= -6
static __device__ inline h16x8 cat44(h16x4 a, h16x4 b) {
    h16x8 r;
    r[0] = a[0]; r[1] = a[1]; r[2] = a[2]; r[3] = a[3];
    r[4] = b[0]; r[5] = b[1]; r[6] = b[2]; r[7] = b[3];
    return r;
}

// feats channel order (new pos -> original W1 input channel):
// {I0, I1, I2, dark | tg, A0, A1, A2} = cmap {0,1,2,4,3,5,6,7}
__constant__ int cmap_dummy;   // (kept trivial; map inlined below)

// ------- gray + horizontal box + featsA{I0,I1,I2,dark}; block 0 packs weights -------
__global__ __launch_bounds__(256) void k_gray_hbox4(const float* __restrict__ I,
                                                    const float* __restrict__ p,
                                                    const float* __restrict__ dark,
                                                    float* __restrict__ g,
                                                    f32x4* __restrict__ hq,
                                                    _Float16* __restrict__ featsA,
                                                    const float* __restrict__ W1,
                                                    const float* __restrict__ W2,
                                                    _Float16* __restrict__ wf1,
                                                    _Float16* __restrict__ wf2) {
    __shared__ float sg[WW], sp[WW];
    int row = blockIdx.x;            // b*HH + y
    int b = row >> 9;
    int base = row * WW;
    const float* Ib = I + (size_t)b * 3 * HW + (size_t)(row & 511) * WW;
    const float* db = dark + (size_t)base;
    int tid = threadIdx.x;
    for (int x = tid; x < WW; x += 256) {
        float i0 = Ib[x], i1 = Ib[HW + x], i2 = Ib[2 * HW + x];
        float gv = 0.299f * i0 + 0.587f * i1 + 0.114f * i2;
        sg[x] = gv; sp[x] = p[base + x];
        g[base + x] = gv;
        h16x4 v;
        v[0] = (_Float16)i0; v[1] = (_Float16)i1; v[2] = (_Float16)i2;
        v[3] = (_Float16)db[x];
        *(h16x4*)(featsA + ((size_t)base + x) * 4) = v;
    }
    __syncthreads();
    for (int x = tid; x < WW; x += 256) {
        float s0 = 0.f, s1 = 0.f, s2 = 0.f, s3v = 0.f;
        int lo = x - RAD < 0 ? 0 : x - RAD;
        int hi = x + RAD >= WW ? WW - 1 : x + RAD;
        for (int i = lo; i <= hi; ++i) {
            float gv = sg[i], pv = sp[i];
            s0 += gv; s1 += pv; s2 += gv * pv; s3v += gv * gv;
        }
        f32x4 o = { s0 * INV_K, s1 * INV_K, s2 * INV_K, s3v * INV_K };
        hq[base + x] = o;
    }
    // ---- weight fragment prepack (block 0, first wave) ----
    if (blockIdx.x == 0 && tid < 64) {
        int lane = tid;
        int j = lane & 15, gg = lane >> 4;
        const int cmap[8] = {0, 1, 2, 4, 3, 5, 6, 7};
#pragma unroll
        for (int cg = 0; cg < 2; ++cg)
#pragma unroll
            for (int t = 0; t < 3; ++t) {
                int s = t * 4 + gg;
                h16x8 w;
#pragma unroll
                for (int i = 0; i < 8; ++i)
                    w[i] = (s < 9) ? (_Float16)W1[(cg * 16 + j) * 72 + cmap[i] * 9 + s]
                                   : (_Float16)0.f;
                *(h16x8*)(wf1 + ((cg * 3 + t) * 64 + lane) * 8) = w;
            }
        int ci0 = gg * 8;
#pragma unroll
        for (int s = 0; s < 9; ++s) {
            h16x8 w;
#pragma unroll
            for (int i = 0; i < 8; ++i)
                w[i] = (_Float16)W2[j * 288 + (ci0 + i) * 9 + s];
            *(h16x8*)(wf2 + (s * 64 + lane) * 8) = w;
        }
    }
}

// ---------------- vertical box of hq, fused a/b ----------------
__global__ __launch_bounds__(256) void k_vbox4_ab(const f32x4* __restrict__ hq,
                                                  f32x2* __restrict__ ab) {
    int x = blockIdx.x * 256 + threadIdx.x;
    int b = blockIdx.y;
    int y0 = blockIdx.z * SEG;
    int pbase = b * HW + x;
    f32x4 s = { 0.f, 0.f, 0.f, 0.f };
    int r0 = y0 - RAD < 0 ? 0 : y0 - RAD;
    for (int r = r0; r < y0 + RAD; ++r) s += hq[pbase + r * WW];
    for (int y = y0; y < y0 + SEG; ++y) {
        if (y + RAD < HH) s += hq[pbase + (y + RAD) * WW];
        float mI = s[0] * INV_K, mP = s[1] * INV_K, mIp = s[2] * INV_K, mII = s[3] * INV_K;
        float cov = mIp - mI * mP;
        float var = mII - mI * mI;
        float av = cov / (var + EPS);
        float bv = mP - av * mI;
        f32x2 o = { av, bv };
        ab[pbase + y * WW] = o;
        if (y - RAD >= 0) s -= hq[pbase + (y - RAD) * WW];
    }
}

// ---------------- horizontal box of ab ----------------
__global__ __launch_bounds__(256) void k_hbox2(const f32x2* __restrict__ ab,
                                               f32x2* __restrict__ hab) {
    __shared__ float sa[WW], sb[WW];
    int base = blockIdx.x * WW;
    int tid = threadIdx.x;
    for (int x = tid; x < WW; x += 256) {
        f32x2 v = ab[base + x];
        sa[x] = v[0]; sb[x] = v[1];
    }
    __syncthreads();
    for (int x = tid; x < WW; x += 256) {
        float s0 = 0.f, s1 = 0.f;
        int lo = x - RAD < 0 ? 0 : x - RAD;
        int hi = x + RAD >= WW ? WW - 1 : x + RAD;
        for (int i = lo; i <= hi; ++i) { s0 += sa[i]; s1 += sb[i]; }
        f32x2 o = { s0 * INV_K, s1 * INV_K };
        hab[base + x] = o;
    }
}

// ------- vertical box of hab + t_guided -> tg fp32 + featsB{tg,A0,A1,A2} -------
__global__ __launch_bounds__(256) void k_vbox2_tg(const f32x2* __restrict__ hab,
                                                  const float* __restrict__ g,
                                                  const float* __restrict__ A,
                                                  float* __restrict__ tg,
                                                  _Float16* __restrict__ featsB) {
    int x = blockIdx.x * 256 + threadIdx.x;
    int b = blockIdx.y;
    int y0 = blockIdx.z * SEG;
    int pbase = b * HW + x;
    _Float16 A0 = (_Float16)A[b * 3 + 0], A1 = (_Float16)A[b * 3 + 1], A2 = (_Float16)A[b * 3 + 2];
    f32x2 s = { 0.f, 0.f };
    int r0 = y0 - RAD < 0 ? 0 : y0 - RAD;
    for (int r = r0; r < y0 + RAD; ++r) s += hab[pbase + r * WW];
    for (int y = y0; y < y0 + SEG; ++y) {
        if (y + RAD < HH) s += hab[pbase + (y + RAD) * WW];
        int o = pbase + y * WW;
        float val = (s[0] * INV_K) * g[o] + (s[1] * INV_K);
        tg[o] = val;
        h16x4 fv;
        fv[0] = (_Float16)val; fv[1] = A0; fv[2] = A1; fv[3] = A2;
        *(h16x4*)(featsB + (size_t)o * 4) = fv;
        if (y - RAD >= 0) s -= hab[pbase + (y - RAD) * WW];
    }
}

// ---------------- fused conv1+conv2+conv3, single barrier per row ----------------
// h1 LDS row: [NPX px][32 ch] fp16; 16B granule c (=ch/8) at sp = c ^ ((lp>>1)&3)
static __device__ inline h16x8 ld_h1(const _Float16* hrow, int lp, int c) {
    int sp = c ^ ((lp >> 1) & 3);
    return *(const h16x8*)(hrow + lp * 32 + sp * 8);
}
static __device__ inline void st_h1(_Float16* hrow, int lp, int u, h16x4 o) {   // u = ch/4
    int sp = (u >> 1) ^ ((lp >> 1) & 3);
    *(h16x4*)(hrow + lp * 32 + sp * 8 + (u & 1) * 4) = o;
}
// h2 LDS row: [NPX px][16 ch] fp16; granule c at sp = c ^ ((lp>>2)&1)
static __device__ inline void st_h2(_Float16* hrow, int lp, int u, h16x4 o) {   // u = ch/4
    int sp = (u >> 1) ^ ((lp >> 2) & 1);
    *(h16x4*)(hrow + lp * 16 + sp * 8 + (u & 1) * 4) = o;
}

static __device__ inline void load_b1(const _Float16* fbA, const _Float16* fbB,
                                      int r1, int X0, int g, int j, int gq, h16x8 Bg[3]) {
    const h16x4 z4 = {0,0,0,0};
    bool xedgeG = (X0 == 0 && g == 0) || (X0 == 256 && g == 16);
    int gxb = X0 + XOFF + g * 16 + j;
    if (!xedgeG && r1 >= 1 && r1 <= 509) {
#pragma unroll
        for (int t = 0; t < 3; ++t) {
            int s = t * 4 + gq;
            int dy = s / 3 - 1, dx = s - (s / 3) * 3 - 1;
            size_t off = ((size_t)(r1 + dy) * WW + (gxb + dx)) * 4;
            Bg[t] = cat44(*(const h16x4*)(fbA + off), *(const h16x4*)(fbB + off));
        }
    } else {
#pragma unroll
        for (int t = 0; t < 3; ++t) {
            int s = t * 4 + gq;
            int dy = s / 3 - 1, dx = s - (s / 3) * 3 - 1;
            int yy = r1 + dy, xx = gxb + dx;
            bool ok = (s < 9) && yy >= 0 && yy < HH && xx >= 0 && xx < WW;
            int yc = yy < 0 ? 0 : (yy > HH - 1 ? HH - 1 : yy);
            int xc = xx < 0 ? 0 : (xx > WW - 1 ? WW - 1 : xx);
            size_t off = ((size_t)yc * WW + xc) * 4;
            h16x4 a = *(const h16x4*)(fbA + off);
            h16x4 bb = *(const h16x4*)(fbB + off);
            Bg[t] = cat44(ok ? a : z4, ok ? bb : z4);
        }
    }
}

__global__ __launch_bounds__(512, 2) void k_cnn_fused(const _Float16* __restrict__ featsA,
                                                      const _Float16* __restrict__ featsB,
                                                      const _Float16* __restrict__ wf1,
                                                      const _Float16* __restrict__ wf2,
                                                      const float* __restrict__ b1,
                                                      const float* __restrict__ b2,
                                                      const float* __restrict__ W3,
                                                      const float* __restrict__ b3,
                                                      const float* __restrict__ tg,
                                                      float* __restrict__ out) {
    __shared__ _Float16 h1s[3][NPX * 32];    // 52,224 B
    __shared__ _Float16 h2s2[2][NPX * 16];   // 17,408 B (slot parity = row & 1)
    __shared__ h16x8 wf1s[6 * 64];           //  6,144 B
    __shared__ h16x2 w3s[72];
    __shared__ float sB[48];                 // b1[32], b2[16]
    __shared__ float w3bias;

    int tid = threadIdx.x;
    int lane = tid & 63, wave = tid >> 6;
    int j = lane & 15, gq = lane >> 4;
    int b = blockIdx.y;
    int X0 = (blockIdx.x & 1) * 256;
    int y0 = (blockIdx.x >> 1) * TROWS;
    const _Float16* fbA = featsA + (size_t)b * HW * 4;
    const _Float16* fbB = featsB + (size_t)b * HW * 4;
    const float* tgb = tg + (size_t)b * HW;
    float* outb = out + (size_t)b * HW;

    // stage wf1 into LDS (384 x 16B), wA2 into regs
    for (int q = tid; q < 384; q += 512)
        ((i32x4*)wf1s)[q] = ((const i32x4*)wf1)[q];
    const h16x8* wf2v = (const h16x8*)wf2;
    h16x8 wA2[9];
#pragma unroll
    for (int s = 0; s < 9; ++s) wA2[s] = wf2v[s * 64 + lane];
    if (tid < 72) {
        int s = tid >> 3, u = tid & 7;
        h16x2 w;
        w[0] = (_Float16)W3[(2 * u) * 9 + s];
        w[1] = (_Float16)W3[(2 * u + 1) * 9 + s];
        w3s[tid] = w;
    } else if (tid < 104) {
        sB[tid - 72] = b1[tid - 72];
    } else if (tid < 120) {
        sB[32 + tid - 104] = b2[tid - 104];
    } else if (tid == 120) w3bias = b3[0];
    __syncthreads();

    int g0 = wave * 2;
    const h16x8 z16 = {0,0,0,0,0,0,0,0};
    h16x8 Bv[2][3];                  // conv1 B prefetch, groups {g0, g0+1}
    h16x8 Bg[3];                     // g16 conv1 B (wave 4)
    f32x4 cA[2] = {}, cB[2] = {}, cC[2] = {};   // conv2 scatter accs
    f32x4 gA = {}, gB = {}, gC = {};            // g16 scatter accs (wave 4)
    int c3px = tid >> 1, c3h = tid & 1;
    float accN = 0.f, accC3 = 0.f;

    for (int i = 0; i < TROWS + 6; ++i) {       // 22 iterations, 1 barrier each
        int r1 = y0 + i - 2;          // conv1 produces h1[r1]
        int rp = y0 + i - 3;          // conv2-scatter consumes h1[rp]
        int r2 = y0 + i - 4;          // h2 row completed + stored
        int R  = y0 + i - 5;          // h2 row conv3 reads (written last iter)
        bool do_h1 = (i <= TROWS + 3) && (r1 >= 0) && (r1 <= 511);
        bool do_rp = (i >= 1) && (i <= TROWS + 4) && (rp >= 0) && (rp <= 511);
        bool st_r2 = (i <= TROWS + 4) && (r2 >= 0) && (r2 <= 511);
        bool rd_R  = (R >= 0) && (R <= 511);

        // ---- A: issue conv1 global loads + tg prefetch (drain under B/C/D) ----
        if (do_h1) {
#pragma unroll
            for (int k = 0; k < 2; ++k)
                load_b1(fbA, fbB, r1, X0, g0 + k, j, gq, Bv[k]);
            if (wave == 4) load_b1(fbA, fbB, r1, X0, 16, j, gq, Bg);
        }
        float tgv = 0.f;
        int oOut = (y0 + i - 6) * WW + X0 + c3px;
        if (i >= 6 && c3h == 0) tgv = tgb[oOut];

        // ---- B: conv2 scatter — read h1[rp] once, update 3 row-accs ----
        f32x4 bias2v = *(const f32x4*)(sB + 32 + gq * 4);
#pragma unroll
        for (int k = 0; k < 2; ++k) {
            cA[k] = cB[k]; cB[k] = cC[k]; cC[k] = bias2v;
        }
        if (wave == 4) { gA = gB; gB = gC; gC = bias2v; }
        if (do_rp) {
            const _Float16* hrow = h1s[s3(rp)];
#pragma unroll
            for (int k = 0; k < 2; ++k) {
                int lpb = (g0 + k) * 16 + j;
#pragma unroll
                for (int dx = 0; dx < 3; ++dx) {
                    int lpx = lpb + dx - 1;
                    h16x8 v;
                    if (wave == 0 && k == 0) {
                        int lpc = lpx < 0 ? 0 : lpx;
                        v = ld_h1(hrow, lpc, gq);
                        if (X0 == 0) v = (lpx >= 8) ? v : z16;   // src x >= 0
                    } else {
                        v = ld_h1(hrow, lpx, gq);
                    }
                    cC[k] = __builtin_amdgcn_mfma_f32_16x16x32_f16(wA2[0 + dx], v, cC[k], 0, 0, 0);
                    cB[k] = __builtin_amdgcn_mfma_f32_16x16x32_f16(wA2[3 + dx], v, cB[k], 0, 0, 0);
                    cA[k] = __builtin_amdgcn_mfma_f32_16x16x32_f16(wA2[6 + dx], v, cA[k], 0, 0, 0);
                }
            }
            if (wave == 4) {                      // group 16 scatter
                int lpb = 256 + j;
#pragma unroll
                for (int dx = 0; dx < 3; ++dx) {
                    int lpx = lpb + dx - 1;       // 255..272
                    int lpc = lpx > NPX - 1 ? NPX - 1 : lpx;
                    h16x8 v = ld_h1(hrow, lpc, gq);
                    if (X0 == 256 && lpx > 263) v = z16;   // src x < WW
                    gC = __builtin_amdgcn_mfma_f32_16x16x32_f16(wA2[0 + dx], v, gC, 0, 0, 0);
                    gB = __builtin_amdgcn_mfma_f32_16x16x32_f16(wA2[3 + dx], v, gB, 0, 0, 0);
                    gA = __builtin_amdgcn_mfma_f32_16x16x32_f16(wA2[6 + dx], v, gA, 0, 0, 0);
                }
            }
        }

        // ---- C: store completed h2 row r2 (slot r2&1; conv3 reads slot R&1) ----
        if (st_r2) {
            _Float16* h2row = h2s2[r2 & 1];
#pragma unroll
            for (int k = 0; k < 2; ++k) {
                h16x4 o;
#pragma unroll
                for (int r = 0; r < 4; ++r) o[r] = (_Float16)fmaxf(cA[k][r], 0.f);
                st_h2(h2row, (g0 + k) * 16 + j, gq, o);
            }
            if (wave == 4) {
                h16x4 o;
#pragma unroll
                for (int r = 0; r < 4; ++r) o[r] = (_Float16)fmaxf(gA[r], 0.f);
                st_h2(h2row, 256 + j, gq, o);
            }
        }

        // ---- D: conv3 running-partials on h2 row R (written last iter) ----
        {
            float d0 = 0.f, d1 = 0.f, d2 = 0.f;
            if (rd_R) {
                const _Float16* hrow = h2s2[R & 1];
#pragma unroll
                for (int dx = 0; dx < 3; ++dx) {
                    int xim = X0 + c3px + dx - 1;
                    if (xim >= 0 && xim < WW) {
                        int lpx = c3px + 8 + dx - 1;
                        int sp = c3h ^ ((lpx >> 2) & 1);
                        h16x8 v = *(const h16x8*)(hrow + lpx * 16 + sp * 8);
#pragma unroll
                        for (int q = 0; q < 4; ++q) {
                            h16x2 pv = { v[2 * q], v[2 * q + 1] };
                            d0 = __builtin_amdgcn_fdot2(pv, w3s[(0 + dx) * 8 + 4 * c3h + q], d0, false);
                            d1 = __builtin_amdgcn_fdot2(pv, w3s[(3 + dx) * 8 + 4 * c3h + q], d1, false);
                            d2 = __builtin_amdgcn_fdot2(pv, w3s[(6 + dx) * 8 + 4 * c3h + q], d2, false);
                        }
                    }
                }
            }
            if (i >= 6) {
                float accv = accC3 + d2;
                float full = accv + __shfl_xor(accv, 1) + w3bias;
                if (c3h == 0) {
                    float sg = 1.f / (1.f + expf(-full));
                    float tf = 0.7f * tgv + 0.3f * sg;
                    outb[oOut] = fminf(fmaxf(tf, 0.f), 1.f);
                }
            }
            accC3 = accN + d1;
            accN = d0;
        }

        // ---- E: conv1 MFMA (Bv drained) + store h1 row r1 ----
        if (do_h1) {
            h16x8 w1[2][3];
#pragma unroll
            for (int cg = 0; cg < 2; ++cg)
#pragma unroll
                for (int t = 0; t < 3; ++t) w1[cg][t] = wf1s[(cg * 3 + t) * 64 + lane];
            _Float16* h1row = h1s[s3(r1)];
            f32x4 b1lo = *(const f32x4*)(sB + gq * 4);
            f32x4 b1hi = *(const f32x4*)(sB + 16 + gq * 4);
#pragma unroll
            for (int k = 0; k < 2; ++k) {
                f32x4 a1[2] = { b1lo, b1hi };
#pragma unroll
                for (int t = 0; t < 3; ++t)
#pragma unroll
                    for (int cg = 0; cg < 2; ++cg)
                        a1[cg] = __builtin_amdgcn_mfma_f32_16x16x32_f16(w1[cg][t], Bv[k][t], a1[cg], 0, 0, 0);
                int lp = (g0 + k) * 16 + j;
#pragma unroll
                for (int cg = 0; cg < 2; ++cg) {
                    h16x4 o;
#pragma unroll
                    for (int r = 0; r < 4; ++r) o[r] = (_Float16)fmaxf(a1[cg][r], 0.f);
                    st_h1(h1row, lp, cg * 4 + gq, o);
                }
            }
            if (wave == 4) {
                f32x4 a1[2] = { b1lo, b1hi };
#pragma unroll
                for (int t = 0; t < 3; ++t)
#pragma unroll
                    for (int cg = 0; cg < 2; ++cg)
                        a1[cg] = __builtin_amdgcn_mfma_f32_16x16x32_f16(w1[cg][t], Bg[t], a1[cg], 0, 0, 0);
                int lp = 256 + j;
#pragma unroll
                for (int cg = 0; cg < 2; ++cg) {
                    h16x4 o;
#pragma unroll
                    for (int r = 0; r < 4; ++r) o[r] = (_Float16)fmaxf(a1[cg][r], 0.f);
                    st_h1(h1row, lp, cg * 4 + gq, o);
                }
            }
        }
        __syncthreads();
    }
}

extern "C" void kernel_launch(void* const* d_in, const int* in_sizes, int n_in,
                              void* d_out, int out_size, void* d_ws, size_t ws_size,
                              hipStream_t stream) {
    const float* I    = (const float*)d_in[0];
    const float* t0   = (const float*)d_in[1];
    const float* dark = (const float*)d_in[2];
    const float* A    = (const float*)d_in[3];
    const float* W1   = (const float*)d_in[4];
    const float* b1   = (const float*)d_in[5];
    const float* W2   = (const float*)d_in[6];
    const float* b2   = (const float*)d_in[7];
    const float* W3   = (const float*)d_in[8];
    const float* b3   = (const float*)d_in[9];
    float* out = (float*)d_out;
    float* ws  = (float*)d_ws;

    const size_t P = (size_t)BB * HW;       // 2M floats = 8 MB
    float* tg        = ws;                       // [0,P)   fp32
    _Float16* featsA = (_Float16*)(ws + P);      // [P,3P)  h16x4/px
    _Float16* featsB = (_Float16*)(ws + 3 * P);  // [3P,5P) h16x4/px
    float* g         = ws + 5 * P;               // [5P,6P)
    f32x4* hq        = (f32x4*)(ws + 6 * P);     // [6P,10P)
    f32x2* ab        = (f32x2*)(ws + 10 * P);    // [10P,12P)
    f32x2* hab       = (f32x2*)(ws + 12 * P);    // [12P,14P)
    _Float16* wf1    = (_Float16*)(ws + 14 * P); // 3072 halves
    _Float16* wf2    = wf1 + 6 * 64 * 8;         // 4608 halves

    k_gray_hbox4<<<BB * HH, 256, 0, stream>>>(I, t0, dark, g, hq, featsA, W1, W2, wf1, wf2);
    dim3 gv(WW / 256, BB, HH / SEG);
    k_vbox4_ab<<<gv, 256, 0, stream>>>(hq, ab);
    k_hbox2<<<BB * HH, 256, 0, stream>>>(ab, hab);
    k_vbox2_tg<<<gv, 256, 0, stream>>>(hab, g, A, tg, featsB);

    dim3 gf(64, BB);                        // 32 y-tiles x 2 x-halves x 8 batches
    k_cnn_fused<<<gf, 512, 0, stream>>>(featsA, featsB, wf1, wf2, b1, b2, W3, b3, tg, out);
}

// Round 13
// 192.252 us; speedup vs baseline: 1.2092x; 1.0353x over previous
//
#include <hip/hip_runtime.h>
#include <cmath>

#define BB 8
#define HH 512
#define WW 512
#define HW (HH*WW)
#define RAD 15
#define SEG 16
#define EPS 0.001f
#define INV_K (1.0f/31.0f)
#define TROWS 16
#define NPX 272            // computed px per block: 256 out + 16 halo
#define XOFF (-8)

typedef _Float16 h16x8 __attribute__((ext_vector_type(8)));
typedef _Float16 h16x4 __attribute__((ext_vector_type(4)));
typedef _Float16 h16x2 __attribute__((ext_vector_type(2)));
typedef float f32x4 __attribute__((ext_vector_type(4)));
typedef float f32x2 __attribute__((ext_vector_type(2)));
typedef int   i32x4 __attribute__((ext_vector_type(4)));

static __device__ inline int s3(int r) { return (r + 6) % 3; }   // r >= -6

// feats channel order: {I0, I1, I2, dark | tg, A0, A1, A2} -> W1 cmap {0,1,2,4,3,5,6,7}

// ------- gray + horizontal box + feats ch0-3; block 0 packs weights -------
__global__ __launch_bounds__(256) void k_gray_hbox4(const float* __restrict__ I,
                                                    const float* __restrict__ p,
                                                    const float* __restrict__ dark,
                                                    float* __restrict__ g,
                                                    f32x4* __restrict__ hq,
                                                    _Float16* __restrict__ feats,
                                                    const float* __restrict__ W1,
                                                    const float* __restrict__ W2,
                                                    _Float16* __restrict__ wf1,
                                                    _Float16* __restrict__ wf2) {
    __shared__ float sg[WW], sp[WW];
    int row = blockIdx.x;            // b*HH + y
    int b = row >> 9;
    int base = row * WW;
    const float* Ib = I + (size_t)b * 3 * HW + (size_t)(row & 511) * WW;
    const float* db = dark + (size_t)base;
    int tid = threadIdx.x;
    for (int x = tid; x < WW; x += 256) {
        float i0 = Ib[x], i1 = Ib[HW + x], i2 = Ib[2 * HW + x];
        float gv = 0.299f * i0 + 0.587f * i1 + 0.114f * i2;
        sg[x] = gv; sp[x] = p[base + x];
        g[base + x] = gv;
        h16x4 v;
        v[0] = (_Float16)i0; v[1] = (_Float16)i1; v[2] = (_Float16)i2;
        v[3] = (_Float16)db[x];
        *(h16x4*)(feats + ((size_t)base + x) * 8) = v;
    }
    __syncthreads();
    for (int x = tid; x < WW; x += 256) {
        float s0 = 0.f, s1 = 0.f, s2 = 0.f, s3v = 0.f;
        int lo = x - RAD < 0 ? 0 : x - RAD;
        int hi = x + RAD >= WW ? WW - 1 : x + RAD;
        for (int i = lo; i <= hi; ++i) {
            float gv = sg[i], pv = sp[i];
            s0 += gv; s1 += pv; s2 += gv * pv; s3v += gv * gv;
        }
        f32x4 o = { s0 * INV_K, s1 * INV_K, s2 * INV_K, s3v * INV_K };
        hq[base + x] = o;
    }
    // ---- weight fragment prepack (block 0, first wave) ----
    if (blockIdx.x == 0 && tid < 64) {
        int lane = tid;
        int j = lane & 15, gg = lane >> 4;
        const int cmap[8] = {0, 1, 2, 4, 3, 5, 6, 7};
#pragma unroll
        for (int cg = 0; cg < 2; ++cg)
#pragma unroll
            for (int t = 0; t < 3; ++t) {
                int s = t * 4 + gg;
                h16x8 w;
#pragma unroll
                for (int i = 0; i < 8; ++i)
                    w[i] = (s < 9) ? (_Float16)W1[(cg * 16 + j) * 72 + cmap[i] * 9 + s]
                                   : (_Float16)0.f;
                *(h16x8*)(wf1 + ((cg * 3 + t) * 64 + lane) * 8) = w;
            }
        int ci0 = gg * 8;
#pragma unroll
        for (int s = 0; s < 9; ++s) {
            h16x8 w;
#pragma unroll
            for (int i = 0; i < 8; ++i)
                w[i] = (_Float16)W2[j * 288 + (ci0 + i) * 9 + s];
            *(h16x8*)(wf2 + (s * 64 + lane) * 8) = w;
        }
    }
}

// ---------------- vertical box of hq, fused a/b ----------------
__global__ __launch_bounds__(256) void k_vbox4_ab(const f32x4* __restrict__ hq,
                                                  f32x2* __restrict__ ab) {
    int x = blockIdx.x * 256 + threadIdx.x;
    int b = blockIdx.y;
    int y0 = blockIdx.z * SEG;
    int pbase = b * HW + x;
    f32x4 s = { 0.f, 0.f, 0.f, 0.f };
    int r0 = y0 - RAD < 0 ? 0 : y0 - RAD;
    for (int r = r0; r < y0 + RAD; ++r) s += hq[pbase + r * WW];
    for (int y = y0; y < y0 + SEG; ++y) {
        if (y + RAD < HH) s += hq[pbase + (y + RAD) * WW];
        float mI = s[0] * INV_K, mP = s[1] * INV_K, mIp = s[2] * INV_K, mII = s[3] * INV_K;
        float cov = mIp - mI * mP;
        float var = mII - mI * mI;
        float av = cov / (var + EPS);
        float bv = mP - av * mI;
        f32x2 o = { av, bv };
        ab[pbase + y * WW] = o;
        if (y - RAD >= 0) s -= hq[pbase + (y - RAD) * WW];
    }
}

// ---------------- horizontal box of ab ----------------
__global__ __launch_bounds__(256) void k_hbox2(const f32x2* __restrict__ ab,
                                               f32x2* __restrict__ hab) {
    __shared__ float sa[WW], sb[WW];
    int base = blockIdx.x * WW;
    int tid = threadIdx.x;
    for (int x = tid; x < WW; x += 256) {
        f32x2 v = ab[base + x];
        sa[x] = v[0]; sb[x] = v[1];
    }
    __syncthreads();
    for (int x = tid; x < WW; x += 256) {
        float s0 = 0.f, s1 = 0.f;
        int lo = x - RAD < 0 ? 0 : x - RAD;
        int hi = x + RAD >= WW ? WW - 1 : x + RAD;
        for (int i = lo; i <= hi; ++i) { s0 += sa[i]; s1 += sb[i]; }
        f32x2 o = { s0 * INV_K, s1 * INV_K };
        hab[base + x] = o;
    }
}

// ------- vertical box of hab + t_guided -> tg fp32 + feats ch4-7 -------
__global__ __launch_bounds__(256) void k_vbox2_tg(const f32x2* __restrict__ hab,
                                                  const float* __restrict__ g,
                                                  const float* __restrict__ A,
                                                  float* __restrict__ tg,
                                                  _Float16* __restrict__ feats) {
    int x = blockIdx.x * 256 + threadIdx.x;
    int b = blockIdx.y;
    int y0 = blockIdx.z * SEG;
    int pbase = b * HW + x;
    _Float16 A0 = (_Float16)A[b * 3 + 0], A1 = (_Float16)A[b * 3 + 1], A2 = (_Float16)A[b * 3 + 2];
    f32x2 s = { 0.f, 0.f };
    int r0 = y0 - RAD < 0 ? 0 : y0 - RAD;
    for (int r = r0; r < y0 + RAD; ++r) s += hab[pbase + r * WW];
    for (int y = y0; y < y0 + SEG; ++y) {
        if (y + RAD < HH) s += hab[pbase + (y + RAD) * WW];
        int o = pbase + y * WW;
        float val = (s[0] * INV_K) * g[o] + (s[1] * INV_K);
        tg[o] = val;
        h16x4 fv;
        fv[0] = (_Float16)val; fv[1] = A0; fv[2] = A1; fv[3] = A2;
        *(h16x4*)(feats + (size_t)o * 8 + 4) = fv;
        if (y - RAD >= 0) s -= hab[pbase + (y - RAD) * WW];
    }
}

// ---------------- fused conv1+conv2+conv3, single barrier per row ----------------
// h1 LDS row: [NPX px][32 ch] fp16; 16B granule c (=ch/8) at sp = c ^ ((lp>>1)&3)
static __device__ inline h16x8 ld_h1(const _Float16* hrow, int lp, int c) {
    int sp = c ^ ((lp >> 1) & 3);
    return *(const h16x8*)(hrow + lp * 32 + sp * 8);
}
static __device__ inline void st_h1(_Float16* hrow, int lp, int u, h16x4 o) {   // u = ch/4
    int sp = (u >> 1) ^ ((lp >> 1) & 3);
    *(h16x4*)(hrow + lp * 32 + sp * 8 + (u & 1) * 4) = o;
}
// h2 LDS row: [NPX px][16 ch] fp16; granule c at sp = c ^ ((lp>>2)&1)
static __device__ inline void st_h2(_Float16* hrow, int lp, int u, h16x4 o) {   // u = ch/4
    int sp = (u >> 1) ^ ((lp >> 2) & 1);
    *(h16x4*)(hrow + lp * 16 + sp * 8 + (u & 1) * 4) = o;
}

static __device__ inline void load_b1(const _Float16* fb, int r1, int X0, int g,
                                      int j, int gq, h16x8 Bg[3]) {
    const h16x8 z = {0,0,0,0,0,0,0,0};
    bool xedgeG = (X0 == 0 && g == 0) || (X0 == 256 && g == 16);
    int gxb = X0 + XOFF + g * 16 + j;
    if (!xedgeG && r1 >= 1 && r1 <= 509) {
#pragma unroll
        for (int t = 0; t < 3; ++t) {
            int s = t * 4 + gq;
            int dy = s / 3 - 1, dx = s - (s / 3) * 3 - 1;
            Bg[t] = *(const h16x8*)(fb + ((size_t)(r1 + dy) * WW + (gxb + dx)) * 8);
        }
    } else {
#pragma unroll
        for (int t = 0; t < 3; ++t) {
            int s = t * 4 + gq;
            int dy = s / 3 - 1, dx = s - (s / 3) * 3 - 1;
            int yy = r1 + dy, xx = gxb + dx;
            bool ok = (s < 9) && yy >= 0 && yy < HH && xx >= 0 && xx < WW;
            int yc = yy < 0 ? 0 : (yy > HH - 1 ? HH - 1 : yy);
            int xc = xx < 0 ? 0 : (xx > WW - 1 ? WW - 1 : xx);
            h16x8 v = *(const h16x8*)(fb + ((size_t)yc * WW + xc) * 8);
            Bg[t] = ok ? v : z;
        }
    }
}

__global__ __launch_bounds__(512, 2) void k_cnn_fused(const _Float16* __restrict__ feats,
                                                      const _Float16* __restrict__ wf1,
                                                      const _Float16* __restrict__ wf2,
                                                      const float* __restrict__ b1,
                                                      const float* __restrict__ b2,
                                                      const float* __restrict__ W3,
                                                      const float* __restrict__ b3,
                                                      const float* __restrict__ tg,
                                                      float* __restrict__ out) {
    __shared__ _Float16 h1s[3][NPX * 32];    // 52,224 B
    __shared__ _Float16 h2s2[2][NPX * 16];   // 17,408 B (slot parity = row & 1)
    __shared__ h16x8 wf1s[6 * 64];           //  6,144 B
    __shared__ h16x2 w3s[72];
    __shared__ float sB[48];                 // b1[32], b2[16]
    __shared__ float w3bias;

    int tid = threadIdx.x;
    int lane = tid & 63, wave = tid >> 6;
    int j = lane & 15, gq = lane >> 4;
    int b = blockIdx.y;
    int X0 = (blockIdx.x & 1) * 256;
    int y0 = (blockIdx.x >> 1) * TROWS;
    const _Float16* fb = feats + (size_t)b * HW * 8;
    const float* tgb = tg + (size_t)b * HW;
    float* outb = out + (size_t)b * HW;

    // stage wf1 into LDS (384 x 16B), wA2 into regs
    for (int q = tid; q < 384; q += 512)
        ((i32x4*)wf1s)[q] = ((const i32x4*)wf1)[q];
    const h16x8* wf2v = (const h16x8*)wf2;
    h16x8 wA2[9];
#pragma unroll
    for (int s = 0; s < 9; ++s) wA2[s] = wf2v[s * 64 + lane];
    if (tid < 72) {
        int s = tid >> 3, u = tid & 7;
        h16x2 w;
        w[0] = (_Float16)W3[(2 * u) * 9 + s];
        w[1] = (_Float16)W3[(2 * u + 1) * 9 + s];
        w3s[tid] = w;
    } else if (tid < 104) {
        sB[tid - 72] = b1[tid - 72];
    } else if (tid < 120) {
        sB[32 + tid - 104] = b2[tid - 104];
    } else if (tid == 120) w3bias = b3[0];
    __syncthreads();

    int g0 = wave * 2;
    const h16x8 z16 = {0,0,0,0,0,0,0,0};
    h16x8 Bv[2][3];                  // conv1 B prefetch, groups {g0, g0+1}
    h16x8 Bg[3];                     // g16 conv1 B (wave 4)
    f32x4 cA[2] = {}, cB[2] = {}, cC[2] = {};   // conv2 scatter accs
    f32x4 gA = {}, gB = {}, gC = {};            // g16 scatter accs (wave 4)
    int c3px = tid >> 1, c3h = tid & 1;
    float accN = 0.f, accC3 = 0.f;

    for (int i = 0; i < TROWS + 6; ++i) {       // 22 iterations, 1 barrier each
        int r1 = y0 + i - 2;          // conv1 produces h1[r1]
        int rp = y0 + i - 3;          // conv2-scatter consumes h1[rp]
        int r2 = y0 + i - 4;          // h2 row completed + stored
        int R  = y0 + i - 5;          // h2 row conv3 reads (written last iter)
        bool do_h1 = (i <= TROWS + 3) && (r1 >= 0) && (r1 <= 511);
        bool do_rp = (i >= 1) && (i <= TROWS + 4) && (rp >= 0) && (rp <= 511);
        bool st_r2 = (i <= TROWS + 4) && (r2 >= 0) && (r2 <= 511);
        bool rd_R  = (R >= 0) && (R <= 511);

        // ---- A: issue conv1 global loads + tg prefetch (drain under B/C/D) ----
        if (do_h1) {
#pragma unroll
            for (int k = 0; k < 2; ++k)
                load_b1(fb, r1, X0, g0 + k, j, gq, Bv[k]);
            if (wave == 4) load_b1(fb, r1, X0, 16, j, gq, Bg);
        }
        float tgv = 0.f;
        int oOut = (y0 + i - 6) * WW + X0 + c3px;
        if (i >= 6 && c3h == 0) tgv = tgb[oOut];

        // ---- B: conv2 scatter — read h1[rp] once, update 3 row-accs ----
        f32x4 bias2v = *(const f32x4*)(sB + 32 + gq * 4);
#pragma unroll
        for (int k = 0; k < 2; ++k) {
            cA[k] = cB[k]; cB[k] = cC[k]; cC[k] = bias2v;
        }
        if (wave == 4) { gA = gB; gB = gC; gC = bias2v; }
        if (do_rp) {
            const _Float16* hrow = h1s[s3(rp)];
#pragma unroll
            for (int k = 0; k < 2; ++k) {
                int lpb = (g0 + k) * 16 + j;
#pragma unroll
                for (int dx = 0; dx < 3; ++dx) {
                    int lpx = lpb + dx - 1;
                    h16x8 v;
                    if (wave == 0 && k == 0) {
                        int lpc = lpx < 0 ? 0 : lpx;
                        v = ld_h1(hrow, lpc, gq);
                        if (X0 == 0) v = (lpx >= 8) ? v : z16;   // src x >= 0
                    } else {
                        v = ld_h1(hrow, lpx, gq);
                    }
                    cC[k] = __builtin_amdgcn_mfma_f32_16x16x32_f16(wA2[0 + dx], v, cC[k], 0, 0, 0);
                    cB[k] = __builtin_amdgcn_mfma_f32_16x16x32_f16(wA2[3 + dx], v, cB[k], 0, 0, 0);
                    cA[k] = __builtin_amdgcn_mfma_f32_16x16x32_f16(wA2[6 + dx], v, cA[k], 0, 0, 0);
                }
            }
            if (wave == 4) {                      // group 16 scatter
                int lpb = 256 + j;
#pragma unroll
                for (int dx = 0; dx < 3; ++dx) {
                    int lpx = lpb + dx - 1;       // 255..272
                    int lpc = lpx > NPX - 1 ? NPX - 1 : lpx;
                    h16x8 v = ld_h1(hrow, lpc, gq);
                    if (X0 == 256 && lpx > 263) v = z16;   // src x < WW
                    gC = __builtin_amdgcn_mfma_f32_16x16x32_f16(wA2[0 + dx], v, gC, 0, 0, 0);
                    gB = __builtin_amdgcn_mfma_f32_16x16x32_f16(wA2[3 + dx], v, gB, 0, 0, 0);
                    gA = __builtin_amdgcn_mfma_f32_16x16x32_f16(wA2[6 + dx], v, gA, 0, 0, 0);
                }
            }
        }

        // ---- C: store completed h2 row r2 (slot r2&1; conv3 reads slot R&1) ----
        if (st_r2) {
            _Float16* h2row = h2s2[r2 & 1];
#pragma unroll
            for (int k = 0; k < 2; ++k) {
                h16x4 o;
#pragma unroll
                for (int r = 0; r < 4; ++r) o[r] = (_Float16)fmaxf(cA[k][r], 0.f);
                st_h2(h2row, (g0 + k) * 16 + j, gq, o);
            }
            if (wave == 4) {
                h16x4 o;
#pragma unroll
                for (int r = 0; r < 4; ++r) o[r] = (_Float16)fmaxf(gA[r], 0.f);
                st_h2(h2row, 256 + j, gq, o);
            }
        }

        // ---- D: conv3 running-partials on h2 row R (written last iter) ----
        {
            float d0 = 0.f, d1 = 0.f, d2 = 0.f;
            if (rd_R) {
                const _Float16* hrow = h2s2[R & 1];
#pragma unroll
                for (int dx = 0; dx < 3; ++dx) {
                    int xim = X0 + c3px + dx - 1;
                    if (xim >= 0 && xim < WW) {
                        int lpx = c3px + 8 + dx - 1;
                        int sp = c3h ^ ((lpx >> 2) & 1);
                        h16x8 v = *(const h16x8*)(hrow + lpx * 16 + sp * 8);
#pragma unroll
                        for (int q = 0; q < 4; ++q) {
                            h16x2 pv = { v[2 * q], v[2 * q + 1] };
                            d0 = __builtin_amdgcn_fdot2(pv, w3s[(0 + dx) * 8 + 4 * c3h + q], d0, false);
                            d1 = __builtin_amdgcn_fdot2(pv, w3s[(3 + dx) * 8 + 4 * c3h + q], d1, false);
                            d2 = __builtin_amdgcn_fdot2(pv, w3s[(6 + dx) * 8 + 4 * c3h + q], d2, false);
                        }
                    }
                }
            }
            if (i >= 6) {
                float accv = accC3 + d2;
                float full = accv + __shfl_xor(accv, 1) + w3bias;
                if (c3h == 0) {
                    float sg = 1.f / (1.f + expf(-full));
                    float tf = 0.7f * tgv + 0.3f * sg;
                    outb[oOut] = fminf(fmaxf(tf, 0.f), 1.f);
                }
            }
            accC3 = accN + d1;
            accN = d0;
        }

        // ---- E: conv1 MFMA (Bv drained) + store h1 row r1 ----
        if (do_h1) {
            h16x8 w1[2][3];
#pragma unroll
            for (int cg = 0; cg < 2; ++cg)
#pragma unroll
                for (int t = 0; t < 3; ++t) w1[cg][t] = wf1s[(cg * 3 + t) * 64 + lane];
            _Float16* h1row = h1s[s3(r1)];
            f32x4 b1lo = *(const f32x4*)(sB + gq * 4);
            f32x4 b1hi = *(const f32x4*)(sB + 16 + gq * 4);
#pragma unroll
            for (int k = 0; k < 2; ++k) {
                f32x4 a1[2] = { b1lo, b1hi };
#pragma unroll
                for (int t = 0; t < 3; ++t)
#pragma unroll
                    for (int cg = 0; cg < 2; ++cg)
                        a1[cg] = __builtin_amdgcn_mfma_f32_16x16x32_f16(w1[cg][t], Bv[k][t], a1[cg], 0, 0, 0);
                int lp = (g0 + k) * 16 + j;
#pragma unroll
                for (int cg = 0; cg < 2; ++cg) {
                    h16x4 o;
#pragma unroll
                    for (int r = 0; r < 4; ++r) o[r] = (_Float16)fmaxf(a1[cg][r], 0.f);
                    st_h1(h1row, lp, cg * 4 + gq, o);
                }
            }
            if (wave == 4) {
                f32x4 a1[2] = { b1lo, b1hi };
#pragma unroll
                for (int t = 0; t < 3; ++t)
#pragma unroll
                    for (int cg = 0; cg < 2; ++cg)
                        a1[cg] = __builtin_amdgcn_mfma_f32_16x16x32_f16(w1[cg][t], Bg[t], a1[cg], 0, 0, 0);
                int lp = 256 + j;
#pragma unroll
                for (int cg = 0; cg < 2; ++cg) {
                    h16x4 o;
#pragma unroll
                    for (int r = 0; r < 4; ++r) o[r] = (_Float16)fmaxf(a1[cg][r], 0.f);
                    st_h1(h1row, lp, cg * 4 + gq, o);
                }
            }
        }
        __syncthreads();
    }
}

extern "C" void kernel_launch(void* const* d_in, const int* in_sizes, int n_in,
                              void* d_out, int out_size, void* d_ws, size_t ws_size,
                              hipStream_t stream) {
    const float* I    = (const float*)d_in[0];
    const float* t0   = (const float*)d_in[1];
    const float* dark = (const float*)d_in[2];
    const float* A    = (const float*)d_in[3];
    const float* W1   = (const float*)d_in[4];
    const float* b1   = (const float*)d_in[5];
    const float* W2   = (const float*)d_in[6];
    const float* b2   = (const float*)d_in[7];
    const float* W3   = (const float*)d_in[8];
    const float* b3   = (const float*)d_in[9];
    float* out = (float*)d_out;
    float* ws  = (float*)d_ws;

    const size_t P = (size_t)BB * HW;       // 2M floats = 8 MB
    float* tg       = ws;                       // [0,P)   fp32
    _Float16* feats = (_Float16*)(ws + P);      // [P,5P)  fp16 [B][HW][8]
    float* g        = ws + 5 * P;               // [5P,6P)
    f32x4* hq       = (f32x4*)(ws + 6 * P);     // [6P,10P)
    f32x2* ab       = (f32x2*)(ws + 10 * P);    // [10P,12P)
    f32x2* hab      = (f32x2*)(ws + 12 * P);    // [12P,14P)
    _Float16* wf1   = (_Float16*)(ws + 14 * P); // 3072 halves
    _Float16* wf2   = wf1 + 6 * 64 * 8;         // 4608 halves

    k_gray_hbox4<<<BB * HH, 256, 0, stream>>>(I, t0, dark, g, hq, feats, W1, W2, wf1, wf2);
    dim3 gv(WW / 256, BB, HH / SEG);
    k_vbox4_ab<<<gv, 256, 0, stream>>>(hq, ab);
    k_hbox2<<<BB * HH, 256, 0, stream>>>(ab, hab);
    k_vbox2_tg<<<gv, 256, 0, stream>>>(hab, g, A, tg, feats);

    dim3 gf(64, BB);                        // 32 y-tiles x 2 x-halves x 8 batches
    k_cnn_fused<<<gf, 512, 0, stream>>>(feats, wf1, wf2, b1, b2, W3, b3, tg, out);
}

// Round 14
// 180.951 us; speedup vs baseline: 1.2848x; 1.0625x over previous
//
#include <hip/hip_runtime.h>
#include <cmath>

#define BB 8
#define HH 512
#define WW 512
#define HW (HH*WW)
#define RAD 15
#define SEG 16
#define EPS 0.001f
#define INV_K (1.0f/31.0f)
#define TROWS 16
#define NPX 272            // computed px per block: 256 out + 16 halo
#define XOFF (-8)

typedef _Float16 h16x8 __attribute__((ext_vector_type(8)));
typedef _Float16 h16x4 __attribute__((ext_vector_type(4)));
typedef _Float16 h16x2 __attribute__((ext_vector_type(2)));
typedef float f32x4 __attribute__((ext_vector_type(4)));
typedef float f32x2 __attribute__((ext_vector_type(2)));
typedef int   i32x4 __attribute__((ext_vector_type(4)));

static __device__ inline int s3(int r) { return (r + 6) % 3; }   // r >= -6

// feats channel order: {I0, I1, I2, dark | tg, A0, A1, A2} -> W1 cmap {0,1,2,4,3,5,6,7}

// ------- gray + horizontal box (fp16 hq) + feats ch0-3; block 0 packs weights -------
__global__ __launch_bounds__(256) void k_gray_hbox4(const float* __restrict__ I,
                                                    const float* __restrict__ p,
                                                    const float* __restrict__ dark,
                                                    float* __restrict__ g,
                                                    h16x4* __restrict__ hq,
                                                    _Float16* __restrict__ feats,
                                                    const float* __restrict__ W1,
                                                    const float* __restrict__ W2,
                                                    _Float16* __restrict__ wf1,
                                                    _Float16* __restrict__ wf2) {
    __shared__ float sg[WW], sp[WW];
    int row = blockIdx.x;            // b*HH + y
    int b = row >> 9;
    int base = row * WW;
    const float* Ib = I + (size_t)b * 3 * HW + (size_t)(row & 511) * WW;
    const float* db = dark + (size_t)base;
    int tid = threadIdx.x;
    for (int x = tid; x < WW; x += 256) {
        float i0 = Ib[x], i1 = Ib[HW + x], i2 = Ib[2 * HW + x];
        float gv = 0.299f * i0 + 0.587f * i1 + 0.114f * i2;
        sg[x] = gv; sp[x] = p[base + x];
        g[base + x] = gv;
        h16x4 v;
        v[0] = (_Float16)i0; v[1] = (_Float16)i1; v[2] = (_Float16)i2;
        v[3] = (_Float16)db[x];
        *(h16x4*)(feats + ((size_t)base + x) * 8) = v;
    }
    __syncthreads();
    for (int x = tid; x < WW; x += 256) {
        float s0 = 0.f, s1 = 0.f, s2 = 0.f, s3v = 0.f;
        int lo = x - RAD < 0 ? 0 : x - RAD;
        int hi = x + RAD >= WW ? WW - 1 : x + RAD;
        for (int i = lo; i <= hi; ++i) {
            float gv = sg[i], pv = sp[i];
            s0 += gv; s1 += pv; s2 += gv * pv; s3v += gv * gv;
        }
        h16x4 o;
        o[0] = (_Float16)(s0 * INV_K); o[1] = (_Float16)(s1 * INV_K);
        o[2] = (_Float16)(s2 * INV_K); o[3] = (_Float16)(s3v * INV_K);
        hq[base + x] = o;
    }
    // ---- weight fragment prepack (block 0, first wave) ----
    if (blockIdx.x == 0 && tid < 64) {
        int lane = tid;
        int j = lane & 15, gg = lane >> 4;
        const int cmap[8] = {0, 1, 2, 4, 3, 5, 6, 7};
#pragma unroll
        for (int cg = 0; cg < 2; ++cg)
#pragma unroll
            for (int t = 0; t < 3; ++t) {
                int s = t * 4 + gg;
                h16x8 w;
#pragma unroll
                for (int i = 0; i < 8; ++i)
                    w[i] = (s < 9) ? (_Float16)W1[(cg * 16 + j) * 72 + cmap[i] * 9 + s]
                                   : (_Float16)0.f;
                *(h16x8*)(wf1 + ((cg * 3 + t) * 64 + lane) * 8) = w;
            }
        int ci0 = gg * 8;
#pragma unroll
        for (int s = 0; s < 9; ++s) {
            h16x8 w;
#pragma unroll
            for (int i = 0; i < 8; ++i)
                w[i] = (_Float16)W2[j * 288 + (ci0 + i) * 9 + s];
            *(h16x8*)(wf2 + (s * 64 + lane) * 8) = w;
        }
    }
}

// ---------------- vertical box of hq (fp16), fused a/b -> ab fp16 ----------------
__global__ __launch_bounds__(256) void k_vbox4_ab(const h16x4* __restrict__ hq,
                                                  h16x2* __restrict__ ab) {
    int x = blockIdx.x * 256 + threadIdx.x;
    int b = blockIdx.y;
    int y0 = blockIdx.z * SEG;
    int pbase = b * HW + x;
    f32x4 s = { 0.f, 0.f, 0.f, 0.f };
    int r0 = y0 - RAD < 0 ? 0 : y0 - RAD;
    for (int r = r0; r < y0 + RAD; ++r) {
        h16x4 v = hq[pbase + r * WW];
        s[0] += (float)v[0]; s[1] += (float)v[1]; s[2] += (float)v[2]; s[3] += (float)v[3];
    }
    for (int y = y0; y < y0 + SEG; ++y) {
        if (y + RAD < HH) {
            h16x4 v = hq[pbase + (y + RAD) * WW];
            s[0] += (float)v[0]; s[1] += (float)v[1]; s[2] += (float)v[2]; s[3] += (float)v[3];
        }
        float mI = s[0] * INV_K, mP = s[1] * INV_K, mIp = s[2] * INV_K, mII = s[3] * INV_K;
        float cov = mIp - mI * mP;
        float var = mII - mI * mI;
        float av = cov / (var + EPS);
        float bv = mP - av * mI;
        h16x2 o;
        o[0] = (_Float16)av; o[1] = (_Float16)bv;
        ab[pbase + y * WW] = o;
        if (y - RAD >= 0) {
            h16x4 v = hq[pbase + (y - RAD) * WW];
            s[0] -= (float)v[0]; s[1] -= (float)v[1]; s[2] -= (float)v[2]; s[3] -= (float)v[3];
        }
    }
}

// ---------------- horizontal box of ab (fp16 in/out) ----------------
__global__ __launch_bounds__(256) void k_hbox2(const h16x2* __restrict__ ab,
                                               h16x2* __restrict__ hab) {
    __shared__ float sa[WW], sb[WW];
    int base = blockIdx.x * WW;
    int tid = threadIdx.x;
    for (int x = tid; x < WW; x += 256) {
        h16x2 v = ab[base + x];
        sa[x] = (float)v[0]; sb[x] = (float)v[1];
    }
    __syncthreads();
    for (int x = tid; x < WW; x += 256) {
        float s0 = 0.f, s1 = 0.f;
        int lo = x - RAD < 0 ? 0 : x - RAD;
        int hi = x + RAD >= WW ? WW - 1 : x + RAD;
        for (int i = lo; i <= hi; ++i) { s0 += sa[i]; s1 += sb[i]; }
        h16x2 o;
        o[0] = (_Float16)(s0 * INV_K); o[1] = (_Float16)(s1 * INV_K);
        hab[base + x] = o;
    }
}

// ------- vertical box of hab (fp16) + t_guided -> tg fp32 + feats ch4-7 -------
__global__ __launch_bounds__(256) void k_vbox2_tg(const h16x2* __restrict__ hab,
                                                  const float* __restrict__ g,
                                                  const float* __restrict__ A,
                                                  float* __restrict__ tg,
                                                  _Float16* __restrict__ feats) {
    int x = blockIdx.x * 256 + threadIdx.x;
    int b = blockIdx.y;
    int y0 = blockIdx.z * SEG;
    int pbase = b * HW + x;
    _Float16 A0 = (_Float16)A[b * 3 + 0], A1 = (_Float16)A[b * 3 + 1], A2 = (_Float16)A[b * 3 + 2];
    f32x2 s = { 0.f, 0.f };
    int r0 = y0 - RAD < 0 ? 0 : y0 - RAD;
    for (int r = r0; r < y0 + RAD; ++r) {
        h16x2 v = hab[pbase + r * WW];
        s[0] += (float)v[0]; s[1] += (float)v[1];
    }
    for (int y = y0; y < y0 + SEG; ++y) {
        if (y + RAD < HH) {
            h16x2 v = hab[pbase + (y + RAD) * WW];
            s[0] += (float)v[0]; s[1] += (float)v[1];
        }
        int o = pbase + y * WW;
        float val = (s[0] * INV_K) * g[o] + (s[1] * INV_K);
        tg[o] = val;
        h16x4 fv;
        fv[0] = (_Float16)val; fv[1] = A0; fv[2] = A1; fv[3] = A2;
        *(h16x4*)(feats + (size_t)o * 8 + 4) = fv;
        if (y - RAD >= 0) {
            h16x2 v = hab[pbase + (y - RAD) * WW];
            s[0] -= (float)v[0]; s[1] -= (float)v[1];
        }
    }
}

// ---------------- fused conv1+conv2+conv3, single barrier per row ----------------
// h1 LDS row: [NPX px][32 ch] fp16; 16B granule c (=ch/8) at sp = c ^ ((lp>>1)&3)
static __device__ inline h16x8 ld_h1(const _Float16* hrow, int lp, int c) {
    int sp = c ^ ((lp >> 1) & 3);
    return *(const h16x8*)(hrow + lp * 32 + sp * 8);
}
static __device__ inline void st_h1(_Float16* hrow, int lp, int u, h16x4 o) {   // u = ch/4
    int sp = (u >> 1) ^ ((lp >> 1) & 3);
    *(h16x4*)(hrow + lp * 32 + sp * 8 + (u & 1) * 4) = o;
}
// h2 LDS row: [NPX px][16 ch] fp16; granule c at sp = c ^ ((lp>>2)&1)
static __device__ inline void st_h2(_Float16* hrow, int lp, int u, h16x4 o) {   // u = ch/4
    int sp = (u >> 1) ^ ((lp >> 2) & 1);
    *(h16x4*)(hrow + lp * 16 + sp * 8 + (u & 1) * 4) = o;
}

static __device__ inline void load_b1(const _Float16* fb, int r1, int X0, int g,
                                      int j, int gq, h16x8 Bg[3]) {
    const h16x8 z = {0,0,0,0,0,0,0,0};
    bool xedgeG = (X0 == 0 && g == 0) || (X0 == 256 && g == 16);
    int gxb = X0 + XOFF + g * 16 + j;
    if (!xedgeG && r1 >= 1 && r1 <= 509) {
#pragma unroll
        for (int t = 0; t < 3; ++t) {
            int s = t * 4 + gq;
            int dy = s / 3 - 1, dx = s - (s / 3) * 3 - 1;
            Bg[t] = *(const h16x8*)(fb + ((size_t)(r1 + dy) * WW + (gxb + dx)) * 8);
        }
    } else {
#pragma unroll
        for (int t = 0; t < 3; ++t) {
            int s = t * 4 + gq;
            int dy = s / 3 - 1, dx = s - (s / 3) * 3 - 1;
            int yy = r1 + dy, xx = gxb + dx;
            bool ok = (s < 9) && yy >= 0 && yy < HH && xx >= 0 && xx < WW;
            int yc = yy < 0 ? 0 : (yy > HH - 1 ? HH - 1 : yy);
            int xc = xx < 0 ? 0 : (xx > WW - 1 ? WW - 1 : xx);
            h16x8 v = *(const h16x8*)(fb + ((size_t)yc * WW + xc) * 8);
            Bg[t] = ok ? v : z;
        }
    }
}

__global__ __launch_bounds__(512, 2) void k_cnn_fused(const _Float16* __restrict__ feats,
                                                      const _Float16* __restrict__ wf1,
                                                      const _Float16* __restrict__ wf2,
                                                      const float* __restrict__ b1,
                                                      const float* __restrict__ b2,
                                                      const float* __restrict__ W3,
                                                      const float* __restrict__ b3,
                                                      const float* __restrict__ tg,
                                                      float* __restrict__ out) {
    __shared__ _Float16 h1s[3][NPX * 32];    // 52,224 B
    __shared__ _Float16 h2s2[2][NPX * 16];   // 17,408 B (slot parity = row & 1)
    __shared__ h16x8 wf1s[6 * 64];           //  6,144 B
    __shared__ h16x2 w3s[72];
    __shared__ float sB[48];                 // b1[32], b2[16]
    __shared__ float w3bias;

    int tid = threadIdx.x;
    int lane = tid & 63, wave = tid >> 6;
    int j = lane & 15, gq = lane >> 4;
    int b = blockIdx.y;
    int X0 = (blockIdx.x & 1) * 256;
    int y0 = (blockIdx.x >> 1) * TROWS;
    const _Float16* fb = feats + (size_t)b * HW * 8;
    const float* tgb = tg + (size_t)b * HW;
    float* outb = out + (size_t)b * HW;

    // stage wf1 into LDS (384 x 16B), wA2 into regs
    for (int q = tid; q < 384; q += 512)
        ((i32x4*)wf1s)[q] = ((const i32x4*)wf1)[q];
    const h16x8* wf2v = (const h16x8*)wf2;
    h16x8 wA2[9];
#pragma unroll
    for (int s = 0; s < 9; ++s) wA2[s] = wf2v[s * 64 + lane];
    if (tid < 72) {
        int s = tid >> 3, u = tid & 7;
        h16x2 w;
        w[0] = (_Float16)W3[(2 * u) * 9 + s];
        w[1] = (_Float16)W3[(2 * u + 1) * 9 + s];
        w3s[tid] = w;
    } else if (tid < 104) {
        sB[tid - 72] = b1[tid - 72];
    } else if (tid < 120) {
        sB[32 + tid - 104] = b2[tid - 104];
    } else if (tid == 120) w3bias = b3[0];
    __syncthreads();

    int g0 = wave * 2;
    const h16x8 z16 = {0,0,0,0,0,0,0,0};
    h16x8 Bv[2][3];                  // conv1 B prefetch, groups {g0, g0+1}
    h16x8 Bg[3];                     // g16 conv1 B (wave 5 — conv2-scatter for g16 is wave 4)
    f32x4 cA[2] = {}, cB[2] = {}, cC[2] = {};   // conv2 scatter accs
    f32x4 gA = {}, gB = {}, gC = {};            // g16 scatter accs (wave 4)
    int c3px = tid >> 1, c3h = tid & 1;
    float accN = 0.f, accC3 = 0.f;

    for (int i = 0; i < TROWS + 6; ++i) {       // 22 iterations, 1 barrier each
        int r1 = y0 + i - 2;          // conv1 produces h1[r1]
        int rp = y0 + i - 3;          // conv2-scatter consumes h1[rp]
        int r2 = y0 + i - 4;          // h2 row completed + stored
        int R  = y0 + i - 5;          // h2 row conv3 reads (written last iter)
        bool do_h1 = (i <= TROWS + 3) && (r1 >= 0) && (r1 <= 511);
        bool do_rp = (i >= 1) && (i <= TROWS + 4) && (rp >= 0) && (rp <= 511);
        bool st_r2 = (i <= TROWS + 4) && (r2 >= 0) && (r2 <= 511);
        bool rd_R  = (R >= 0) && (R <= 511);

        // ---- A: issue conv1 global loads + tg prefetch (drain under B/C/D) ----
        if (do_h1) {
#pragma unroll
            for (int k = 0; k < 2; ++k)
                load_b1(fb, r1, X0, g0 + k, j, gq, Bv[k]);
            if (wave == 5) load_b1(fb, r1, X0, 16, j, gq, Bg);
        }
        float tgv = 0.f;
        int oOut = (y0 + i - 6) * WW + X0 + c3px;
        if (i >= 6 && c3h == 0) tgv = tgb[oOut];

        // ---- B: conv2 scatter — read h1[rp] once, update 3 row-accs ----
        f32x4 bias2v = *(const f32x4*)(sB + 32 + gq * 4);
#pragma unroll
        for (int k = 0; k < 2; ++k) {
            cA[k] = cB[k]; cB[k] = cC[k]; cC[k] = bias2v;
        }
        if (wave == 4) { gA = gB; gB = gC; gC = bias2v; }
        if (do_rp) {
            const _Float16* hrow = h1s[s3(rp)];
#pragma unroll
            for (int k = 0; k < 2; ++k) {
                int lpb = (g0 + k) * 16 + j;
#pragma unroll
                for (int dx = 0; dx < 3; ++dx) {
                    int lpx = lpb + dx - 1;
                    h16x8 v;
                    if (wave == 0 && k == 0) {
                        int lpc = lpx < 0 ? 0 : lpx;
                        v = ld_h1(hrow, lpc, gq);
                        if (X0 == 0) v = (lpx >= 8) ? v : z16;   // src x >= 0
                    } else {
                        v = ld_h1(hrow, lpx, gq);
                    }
                    cC[k] = __builtin_amdgcn_mfma_f32_16x16x32_f16(wA2[0 + dx], v, cC[k], 0, 0, 0);
                    cB[k] = __builtin_amdgcn_mfma_f32_16x16x32_f16(wA2[3 + dx], v, cB[k], 0, 0, 0);
                    cA[k] = __builtin_amdgcn_mfma_f32_16x16x32_f16(wA2[6 + dx], v, cA[k], 0, 0, 0);
                }
            }
            if (wave == 4) {                      // group 16 scatter
                int lpb = 256 + j;
#pragma unroll
                for (int dx = 0; dx < 3; ++dx) {
                    int lpx = lpb + dx - 1;       // 255..272
                    int lpc = lpx > NPX - 1 ? NPX - 1 : lpx;
                    h16x8 v = ld_h1(hrow, lpc, gq);
                    if (X0 == 256 && lpx > 263) v = z16;   // src x < WW
                    gC = __builtin_amdgcn_mfma_f32_16x16x32_f16(wA2[0 + dx], v, gC, 0, 0, 0);
                    gB = __builtin_amdgcn_mfma_f32_16x16x32_f16(wA2[3 + dx], v, gB, 0, 0, 0);
                    gA = __builtin_amdgcn_mfma_f32_16x16x32_f16(wA2[6 + dx], v, gA, 0, 0, 0);
                }
            }
        }

        // ---- C: store completed h2 row r2 (slot r2&1; conv3 reads slot R&1) ----
        if (st_r2) {
            _Float16* h2row = h2s2[r2 & 1];
#pragma unroll
            for (int k = 0; k < 2; ++k) {
                h16x4 o;
#pragma unroll
                for (int r = 0; r < 4; ++r) o[r] = (_Float16)fmaxf(cA[k][r], 0.f);
                st_h2(h2row, (g0 + k) * 16 + j, gq, o);
            }
            if (wave == 4) {
                h16x4 o;
#pragma unroll
                for (int r = 0; r < 4; ++r) o[r] = (_Float16)fmaxf(gA[r], 0.f);
                st_h2(h2row, 256 + j, gq, o);
            }
        }

        // ---- D: conv3 running-partials on h2 row R (written last iter) ----
        {
            float d0 = 0.f, d1 = 0.f, d2 = 0.f;
            if (rd_R) {
                const _Float16* hrow = h2s2[R & 1];
#pragma unroll
                for (int dx = 0; dx < 3; ++dx) {
                    int xim = X0 + c3px + dx - 1;
                    if (xim >= 0 && xim < WW) {
                        int lpx = c3px + 8 + dx - 1;
                        int sp = c3h ^ ((lpx >> 2) & 1);
                        h16x8 v = *(const h16x8*)(hrow + lpx * 16 + sp * 8);
#pragma unroll
                        for (int q = 0; q < 4; ++q) {
                            h16x2 pv = { v[2 * q], v[2 * q + 1] };
                            d0 = __builtin_amdgcn_fdot2(pv, w3s[(0 + dx) * 8 + 4 * c3h + q], d0, false);
                            d1 = __builtin_amdgcn_fdot2(pv, w3s[(3 + dx) * 8 + 4 * c3h + q], d1, false);
                            d2 = __builtin_amdgcn_fdot2(pv, w3s[(6 + dx) * 8 + 4 * c3h + q], d2, false);
                        }
                    }
                }
            }
            if (i >= 6) {
                float accv = accC3 + d2;
                float full = accv + __shfl_xor(accv, 1) + w3bias;
                if (c3h == 0) {
                    float sg = 1.f / (1.f + expf(-full));
                    float tf = 0.7f * tgv + 0.3f * sg;
                    outb[oOut] = fminf(fmaxf(tf, 0.f), 1.f);
                }
            }
            accC3 = accN + d1;
            accN = d0;
        }

        // ---- E: conv1 MFMA (Bv drained) + store h1 row r1 ----
        if (do_h1) {
            h16x8 w1[2][3];
#pragma unroll
            for (int cg = 0; cg < 2; ++cg)
#pragma unroll
                for (int t = 0; t < 3; ++t) w1[cg][t] = wf1s[(cg * 3 + t) * 64 + lane];
            _Float16* h1row = h1s[s3(r1)];
            f32x4 b1lo = *(const f32x4*)(sB + gq * 4);
            f32x4 b1hi = *(const f32x4*)(sB + 16 + gq * 4);
#pragma unroll
            for (int k = 0; k < 2; ++k) {
                f32x4 a1[2] = { b1lo, b1hi };
#pragma unroll
                for (int t = 0; t < 3; ++t)
#pragma unroll
                    for (int cg = 0; cg < 2; ++cg)
                        a1[cg] = __builtin_amdgcn_mfma_f32_16x16x32_f16(w1[cg][t], Bv[k][t], a1[cg], 0, 0, 0);
                int lp = (g0 + k) * 16 + j;
#pragma unroll
                for (int cg = 0; cg < 2; ++cg) {
                    h16x4 o;
#pragma unroll
                    for (int r = 0; r < 4; ++r) o[r] = (_Float16)fmaxf(a1[cg][r], 0.f);
                    st_h1(h1row, lp, cg * 4 + gq, o);
                }
            }
            if (wave == 5) {                      // g16 conv1 (off wave 4)
                f32x4 a1[2] = { b1lo, b1hi };
#pragma unroll
                for (int t = 0; t < 3; ++t)
#pragma unroll
                    for (int cg = 0; cg < 2; ++cg)
                        a1[cg] = __builtin_amdgcn_mfma_f32_16x16x32_f16(w1[cg][t], Bg[t], a1[cg], 0, 0, 0);
                int lp = 256 + j;
#pragma unroll
                for (int cg = 0; cg < 2; ++cg) {
                    h16x4 o;
#pragma unroll
                    for (int r = 0; r < 4; ++r) o[r] = (_Float16)fmaxf(a1[cg][r], 0.f);
                    st_h1(h1row, lp, cg * 4 + gq, o);
                }
            }
        }
        __syncthreads();
    }
}

extern "C" void kernel_launch(void* const* d_in, const int* in_sizes, int n_in,
                              void* d_out, int out_size, void* d_ws, size_t ws_size,
                              hipStream_t stream) {
    const float* I    = (const float*)d_in[0];
    const float* t0   = (const float*)d_in[1];
    const float* dark = (const float*)d_in[2];
    const float* A    = (const float*)d_in[3];
    const float* W1   = (const float*)d_in[4];
    const float* b1   = (const float*)d_in[5];
    const float* W2   = (const float*)d_in[6];
    const float* b2   = (const float*)d_in[7];
    const float* W3   = (const float*)d_in[8];
    const float* b3   = (const float*)d_in[9];
    float* out = (float*)d_out;
    float* ws  = (float*)d_ws;

    const size_t P = (size_t)BB * HW;       // 2M floats = 8 MB
    float* tg       = ws;                       // [0,P)    fp32
    _Float16* feats = (_Float16*)(ws + P);      // [P,5P)   fp16 [B][HW][8]
    float* g        = ws + 5 * P;               // [5P,6P)  fp32
    h16x4* hq       = (h16x4*)(ws + 6 * P);     // [6P,8P)  8B/px
    h16x2* ab       = (h16x2*)(ws + 8 * P);     // [8P,9P)  4B/px
    h16x2* hab      = (h16x2*)(ws + 9 * P);     // [9P,10P) 4B/px
    _Float16* wf1   = (_Float16*)(ws + 10 * P); // 3072 halves
    _Float16* wf2   = wf1 + 6 * 64 * 8;         // 4608 halves

    k_gray_hbox4<<<BB * HH, 256, 0, stream>>>(I, t0, dark, g, hq, feats, W1, W2, wf1, wf2);
    dim3 gv(WW / 256, BB, HH / SEG);
    k_vbox4_ab<<<gv, 256, 0, stream>>>(hq, ab);
    k_hbox2<<<BB * HH, 256, 0, stream>>>(ab, hab);
    k_vbox2_tg<<<gv, 256, 0, stream>>>(hab, g, A, tg, feats);

    dim3 gf(64, BB);                        // 32 y-tiles x 2 x-halves x 8 batches
    k_cnn_fused<<<gf, 512, 0, stream>>>(feats, wf1, wf2, b1, b2, W3, b3, tg, out);
}